// Round 6
// baseline (953.416 us; speedup 1.0000x reference)
//
#include <hip/hip_runtime.h>

// ---------------------------------------------------------------------------
// ACARHead forward, bf16-MFMA convs, 3-phase (tap-group) pipelined K-loop.
// Per K-step (32 ch) the 9 taps are processed as 3 groups of fixed dw:
// group g = { t9 = dh*3+g : dh=0..2 }. W rotates through 2 small buffers
// (one group each); X double-buffered per K-step. Phase pattern:
//   [stage(p+1); compute(p); vmcnt(0); s_barrier]   (uniform lifetimes)
// LDS: 2*16KB (X) + 2*12KB (W) = 56.6 KB static -> 2 blocks/CU.
// Activation layout: bf16 [n][p=256][c]; 14x14 payload at rows/cols 1..14.
// ---------------------------------------------------------------------------

typedef __attribute__((ext_vector_type(8))) short bhalf8;
typedef __attribute__((ext_vector_type(4))) float floatx4;

#define ACT_N 131072   // 256*512 bf16 elements per sample
#define W3SZ  2359296  // 512*512*9 (also = blocked per-tensor short count)

__device__ inline float b2f(unsigned short u) {
  union { unsigned int i; float f; } x; x.i = ((unsigned int)u) << 16; return x.f;
}
__device__ inline unsigned short f2b(float f) {
  union { float f; unsigned int i; } x; x.f = f;
  return (unsigned short)((x.i + 0x7FFFu + ((x.i >> 16) & 1u)) >> 16);
}
__device__ inline void gload_lds16(const unsigned short* g, bhalf8* l) {
  __builtin_amdgcn_global_load_lds(
      (const __attribute__((address_space(1))) unsigned int*)(const void*)g,
      (__attribute__((address_space(3))) unsigned int*)(void*)l, 16, 0, 0);
}

// ---- AdaptiveMaxPool3d(1): max over 196, write xp (f32) and out[:,0:1024] ----
__global__ void pool_max_kernel(const float* __restrict__ x, float* __restrict__ xp,
                                float* __restrict__ out) {
  int tid = threadIdx.x;
  int wid = blockIdx.x * 4 + (tid >> 6);   // n*1024 + c
  int lane = tid & 63;
  int n = wid >> 10, c = wid & 1023;
  const float* p = x + (size_t)wid * 196;
  float v = -3.4e38f;
  v = fmaxf(v, p[lane]);
  v = fmaxf(v, p[lane + 64]);
  v = fmaxf(v, p[lane + 128]);
  if (lane < 4) v = fmaxf(v, p[lane + 192]);
#pragma unroll
  for (int off = 32; off >= 1; off >>= 1) v = fmaxf(v, __shfl_xor(v, off));
  if (lane == 0) { xp[wid] = v; out[(size_t)n * 1536 + c] = v; }
}

// ---- bias1[n][o] = sum_{c<1024} w1[o][1024+c] * xp[n][c]  (f32) ----
__global__ void bias1_kernel(const float* __restrict__ w1, const float* __restrict__ xp,
                             float* __restrict__ bias1) {
  int tid = threadIdx.x;
  int wid = blockIdx.x * 4 + (tid >> 6);   // n*512 + o
  int lane = tid & 63;
  int n = wid >> 9, o = wid & 511;
  const float* wr = w1 + (size_t)o * 2048 + 1024;
  const float* xr = xp + (size_t)n * 1024;
  float s = 0.f;
#pragma unroll
  for (int r = 0; r < 16; r++) { int c = lane + r * 64; s += wr[c] * xr[c]; }
#pragma unroll
  for (int off = 32; off >= 1; off >>= 1) s += __shfl_xor(s, off);
  if (lane == 0) bias1[wid] = s;
}

// ---- 3x3 weight prep -> tap-grouped blocked layout ----
// Wg2[tensor][ot(8)][ks(16)][slot u(2304)][8 bf16]:
//   u = g*768 + (dh*4+kg)*64 + o ; data = w[o0+o][ks*32+kg*8+j][dh*3+g]
__global__ __launch_bounds__(256) void wprep3_kernel(
    const float* __restrict__ w2, const float* __restrict__ wq,
    const float* __restrict__ wk, const float* __restrict__ wv,
    const float* __restrict__ wm, unsigned short* __restrict__ Wg2) {
  int ks = blockIdx.x, ot = blockIdx.y, tid = blockIdx.z;
  int t = threadIdx.x;
  const float* src;
  if (tid == 0) src = w2;
  else {
    int d = (tid - 1) >> 2, r = (tid - 1) & 3;
    src = (r == 0 ? wq : r == 1 ? wk : r == 2 ? wv : wm) + (size_t)d * W3SZ;
  }
  __shared__ unsigned short S[64 * 288];
  const float* sb = src + (size_t)ot * 64 * 4608 + (size_t)ks * 288;
  for (int j = 0; j < 72; j++) {
    int flat = j * 256 + t;          // < 18432
    int o = flat / 288, ci = flat % 288;
    S[flat] = f2b(sb[(size_t)o * 4608 + ci]);
  }
  __syncthreads();
  unsigned short* dst = Wg2 + (((size_t)(tid * 8 + ot) * 16 + ks) * 2304) * 8;
#pragma unroll
  for (int s = 0; s < 9; s++) {
    int u = t + s * 256;
    int g = u / 768, rem = u % 768;
    int rl = rem >> 6, o = rem & 63;
    int dh = rl >> 2, kg = rl & 3;
    int t9src = dh * 3 + g;
    bhalf8 v;
#pragma unroll
    for (int j = 0; j < 8; j++) v[j] = (short)S[o * 288 + (kg * 8 + j) * 9 + t9src];
    *(bhalf8*)(dst + (size_t)u * 8) = v;
  }
}

// ---- conv1 weight prep -> blocked: W1g[ot(8)][ks(32)][slot(256)][8] ----
__global__ void w1prep_kernel(const float* __restrict__ w1, unsigned short* __restrict__ W1g) {
  int ks = blockIdx.x, ot = blockIdx.y, t = threadIdx.x;
  int kg = t >> 6, o = t & 63;
  const float* s = w1 + (size_t)(ot * 64 + o) * 2048 + ks * 32 + kg * 8;
  bhalf8 v;
#pragma unroll
  for (int j = 0; j < 8; j++) v[j] = (short)f2b(s[j]);
  *(bhalf8*)(W1g + (((size_t)ot * 32 + ks) * 256 + t) * 8) = v;
}

// ---- feat transpose: feat[img][c][p] f32 -> featT[img][p][c] bf16 ----
__global__ __launch_bounds__(256) void ftprep_kernel(
    const float* __restrict__ feat, unsigned short* __restrict__ featT) {
  int img = blockIdx.z, c0 = blockIdx.y * 64, p0 = blockIdx.x * 64;
  int t = threadIdx.x;
  int a = t >> 6, b = t & 63;
  __shared__ float S[64][65];
#pragma unroll
  for (int j = 0; j < 16; j++) {
    int r = a * 16 + j;
    S[r][b] = feat[((size_t)img * 1024 + c0 + r) * 256 + p0 + b];
  }
  __syncthreads();
#pragma unroll
  for (int j = 0; j < 16; j++) {
    int pl = a * 16 + j;
    featT[((size_t)img * 256 + p0 + pl) * 1024 + c0 + b] = f2b(S[b][pl]);
  }
}

// ---------------------------------------------------------------------------
// Unified MFMA conv, 3-phase tap-group pipeline (TAPS==9) or 1-phase (TAPS==1).
// Block tile 64o x 256p; per-wave 64o x (NREP*16)p; static LDS.
// ---------------------------------------------------------------------------
template <int TAPS, int KTOT, int WAVES, int NREP, int PSPLIT,
          bool RELU, bool ADD, bool BIAS, bool VALID>
__global__ __launch_bounds__(WAVES * 64) void conv_mfma_kernel(
    const unsigned short* __restrict__ Xg, const int* __restrict__ rois,
    const unsigned short* __restrict__ Wg, const float* __restrict__ bias,
    unsigned short* __restrict__ Out) {
  constexpr int THREADS = WAVES * 64;
  constexpr int NK = KTOT / 32;
  constexpr int WBUF = (TAPS == 9) ? 768 : 256;   // slots per W buffer
  static_assert(PSPLIT * WAVES * NREP * 16 == 256, "p coverage");
  static_assert(1024 % THREADS == 0 && WBUF % THREADS == 0, "stage div");
  __shared__ bhalf8 Xs[2][1024];
  __shared__ bhalf8 Wl[2][WBUF];

  int n = blockIdx.y;
  int ot = blockIdx.x / PSPLIT;
  int pq = blockIdx.x % PSPLIT;
  int t = threadIdx.x;
  int wv = t >> 6, l = t & 63, l15 = l & 15, l4 = l >> 4;
  int pbase = (pq * WAVES + wv) * (NREP * 16);
  const unsigned short* xb =
      Xg + (rois ? (size_t)rois[n * 5] * 256 * KTOT : (size_t)n * 256 * KTOT);
  floatx4 acc[4][NREP] = {};

  auto stageX = [&](int xbuf, int ks) {
#pragma unroll
    for (int i = 0; i < 1024 / THREADS; i++) {
      int base = i * THREADS + wv * 64;
      int u = base + l;
      int p = u & 255, kg = u >> 8;
      gload_lds16(xb + (size_t)p * KTOT + ks * 32 + kg * 8, &Xs[xbuf][base]);
    }
  };
  auto stageW = [&](int wbuf, int ks, int g) {
    const unsigned short* wb =
        Wg + (((size_t)ot * NK + ks) * (TAPS == 9 ? 2304 : 256) + g * 768) * 8;
#pragma unroll
    for (int i = 0; i < WBUF / THREADS; i++) {
      int base = i * THREADS + wv * 64;
      gload_lds16(wb + (size_t)(base + l) * 8, &Wl[wbuf][base]);
    }
  };

  stageX(0, 0);
  stageW(0, 0, 0);
  asm volatile("s_waitcnt vmcnt(0)" ::: "memory");
  __builtin_amdgcn_s_barrier();
  __builtin_amdgcn_sched_barrier(0);

  if constexpr (TAPS == 9) {
    for (int ks = 0; ks < NK; ks++) {
#pragma unroll
      for (int g = 0; g < 3; g++) {
        const int wbuf = (ks + g) & 1;
        // stage next phase's data
        if (g < 2) {
          stageW(wbuf ^ 1, ks, g + 1);
        } else if (ks + 1 < NK) {
          stageW(wbuf ^ 1, ks + 1, 0);
          stageX((ks + 1) & 1, ks + 1);
        }
        __builtin_amdgcn_sched_barrier(0);
        // compute group g (dw = g), taps dh=0..2
        const bhalf8* X = Xs[ks & 1];
        const bhalf8* W = Wl[wbuf];
        bhalf8 BW[NREP + 2];
#pragma unroll
        for (int w10 = 0; w10 < NREP + 2; w10++) {
          int row = (pbase + w10 * 16 + l15 + g) & 255;
          BW[w10] = X[l4 * 256 + row];
        }
#pragma unroll
        for (int dh = 0; dh < 3; dh++) {
          bhalf8 A[4];
#pragma unroll
          for (int of = 0; of < 4; of++) A[of] = W[(dh * 4 + l4) * 64 + of * 16 + l15];
#pragma unroll
          for (int of = 0; of < 4; of++)
#pragma unroll
            for (int pf = 0; pf < NREP; pf++)
              acc[of][pf] = __builtin_amdgcn_mfma_f32_16x16x32_bf16(
                  A[of], BW[pf + dh], acc[of][pf], 0, 0, 0);
        }
        asm volatile("s_waitcnt vmcnt(0)" ::: "memory");
        __builtin_amdgcn_s_barrier();
        __builtin_amdgcn_sched_barrier(0);
      }
    }
  } else {
    for (int ks = 0; ks < NK; ks++) {
      const int cb = ks & 1;
      if (ks + 1 < NK) {
        stageX(cb ^ 1, ks + 1);
        stageW(cb ^ 1, ks + 1, 0);
      }
      __builtin_amdgcn_sched_barrier(0);
      const bhalf8* X = Xs[cb];
      const bhalf8* W = Wl[cb];
      bhalf8 B[NREP];
#pragma unroll
      for (int pf = 0; pf < NREP; pf++) {
        int row = (pbase + pf * 16 + l15) & 255;
        B[pf] = X[l4 * 256 + row];
      }
#pragma unroll
      for (int of = 0; of < 4; of++) {
        bhalf8 A = W[l4 * 64 + of * 16 + l15];
#pragma unroll
        for (int pf = 0; pf < NREP; pf++)
          acc[of][pf] = __builtin_amdgcn_mfma_f32_16x16x32_bf16(
              A, B[pf], acc[of][pf], 0, 0, 0);
      }
      asm volatile("s_waitcnt vmcnt(0)" ::: "memory");
      __builtin_amdgcn_s_barrier();
      __builtin_amdgcn_sched_barrier(0);
    }
  }

#pragma unroll
  for (int of = 0; of < 4; of++) {
    int og = ot * 64 + of * 16 + l4 * 4;
    int tensor = og >> 9, ol = og & 511;
#pragma unroll
    for (int pf = 0; pf < NREP; pf++) {
      int p = pbase + pf * 16 + l15;
      int po = p;
      if (VALID) {
        int h = p >> 4, w = p & 15;
        if (h >= 14 || w >= 14) continue;
        po = (h + 1) * 16 + (w + 1);
      }
      unsigned short* dp = Out + (((size_t)tensor * 32 + n) * 256 + po) * 512 + ol;
      float vv[4];
#pragma unroll
      for (int r2 = 0; r2 < 4; r2++) vv[r2] = acc[of][pf][r2];
      if (BIAS) {
#pragma unroll
        for (int r2 = 0; r2 < 4; r2++) vv[r2] += bias[(size_t)n * 512 + ol + r2];
      }
      if (ADD) {
        ushort4 old = *(const ushort4*)dp;
        vv[0] += b2f(old.x); vv[1] += b2f(old.y); vv[2] += b2f(old.z); vv[3] += b2f(old.w);
      }
      if (RELU) {
#pragma unroll
        for (int r2 = 0; r2 < 4; r2++) vv[r2] = fmaxf(vv[r2], 0.f);
      }
      ushort4 st = { f2b(vv[0]), f2b(vv[1]), f2b(vv[2]), f2b(vv[3]) };
      *(ushort4*)dp = st;
    }
  }
}

// ---- att[qn][pp][kn] = (1/sqrt(512)) * sum_c q[qn][pp][c]*k[kn][pp][c] ----
__global__ __launch_bounds__(256) void att2_kernel(
    const unsigned short* __restrict__ q, const unsigned short* __restrict__ k,
    float* __restrict__ att) {
  int kn = blockIdx.x, qn = blockIdx.y;
  int t = threadIdx.x, wv = t >> 6, l = t & 63;
  const unsigned short* qb = q + (size_t)qn * ACT_N;
  const unsigned short* kb = k + (size_t)kn * ACT_N;
  for (int i = wv; i < 196; i += 4) {
    int pp = (i / 14 + 1) * 16 + (i % 14) + 1;
    bhalf8 qv = *(const bhalf8*)(qb + pp * 512 + l * 8);
    bhalf8 kv = *(const bhalf8*)(kb + pp * 512 + l * 8);
    float s = 0.f;
#pragma unroll
    for (int j = 0; j < 8; j++)
      s += b2f((unsigned short)qv[j]) * b2f((unsigned short)kv[j]);
#pragma unroll
    for (int off = 32; off >= 1; off >>= 1) s += __shfl_xor(s, off);
    if (l == 0) att[((size_t)qn * 256 + pp) * 32 + kn] = s * 0.044194173824159216f;
  }
}

// ---- softmax over kn (32 contiguous f32 per (qn,pp)) ----
__global__ void softmax2_kernel(float* __restrict__ att) {
  int qn = blockIdx.x, t = threadIdx.x;
  if (t >= 196) return;
  int pp = (t / 14 + 1) * 16 + (t % 14) + 1;
  float* a = att + ((size_t)qn * 256 + pp) * 32;
  float v[32]; float m = -3.4e38f;
#pragma unroll
  for (int i = 0; i < 32; i++) { v[i] = a[i]; m = fmaxf(m, v[i]); }
  float s = 0.f;
#pragma unroll
  for (int i = 0; i < 32; i++) { v[i] = __expf(v[i] - m); s += v[i]; }
  float inv = 1.f / s;
#pragma unroll
  for (int i = 0; i < 32; i++) a[i] = v[i] * inv;
}

// ---- vf[qn][p][c] = sum_kn att[qn][p][kn]*v[kn][p][c]; border rows -> 0 ----
__global__ __launch_bounds__(256) void vf2_kernel(
    const float* __restrict__ att, const unsigned short* __restrict__ v,
    unsigned short* __restrict__ o) {
  int p = blockIdx.x, t = threadIdx.x;
  int h = p >> 4, w = p & 15;
  if (h < 1 || h > 14 || w < 1 || w > 14) {
    for (int qn = 0; qn < 32; qn++)
      *(unsigned int*)(o + ((size_t)qn * 256 + p) * 512 + t * 2) = 0u;
    return;
  }
  __shared__ float attS[1024];
  __shared__ unsigned short vS[32 * 512];
#pragma unroll
  for (int i = 0; i < 4; i++) {
    int idx = t + i * 256;
    int qn = idx >> 5, kn = idx & 31;
    attS[idx] = att[((size_t)qn * 256 + p) * 32 + kn];
  }
#pragma unroll
  for (int i = 0; i < 8; i++) {
    int u = t + i * 256;
    int kn = u >> 6, cu = (u & 63) * 8;
    *(bhalf8*)&vS[kn * 512 + cu] = *(const bhalf8*)(v + ((size_t)kn * 256 + p) * 512 + cu);
  }
  __syncthreads();
  int c2 = t * 2;
  for (int qn = 0; qn < 32; qn++) {
    float s0 = 0.f, s1 = 0.f;
#pragma unroll
    for (int kn = 0; kn < 32; kn++) {
      float a = attS[qn * 32 + kn];
      unsigned int vv = *(const unsigned int*)&vS[kn * 512 + c2];
      s0 += a * b2f((unsigned short)vv);
      s1 += a * b2f((unsigned short)(vv >> 16));
    }
    unsigned int pkd = (unsigned int)f2b(s0) | ((unsigned int)f2b(s1) << 16);
    *(unsigned int*)(o + ((size_t)qn * 256 + p) * 512 + c2) = pkd;
  }
}

// ---- GroupNorm stats over interior (196 x 512) per n ----
__global__ __launch_bounds__(256) void gnstats2_kernel(
    const unsigned short* __restrict__ x, float* __restrict__ stats) {
  int n = blockIdx.x, t = threadIdx.x;
  const unsigned short* xb = x + (size_t)n * ACT_N;
  float s = 0.f, ss = 0.f;
  for (int i = 0; i < 196; i++) {
    int pp = (i / 14 + 1) * 16 + (i % 14) + 1;
    unsigned int vv = *(const unsigned int*)(xb + pp * 512 + t * 2);
    float a = b2f((unsigned short)vv), b = b2f((unsigned short)(vv >> 16));
    s += a + b; ss += a * a + b * b;
  }
#pragma unroll
  for (int off = 32; off >= 1; off >>= 1) { s += __shfl_xor(s, off); ss += __shfl_xor(ss, off); }
  __shared__ float sm[8];
  int wv = t >> 6, ln = t & 63;
  if (ln == 0) { sm[wv] = s; sm[4 + wv] = ss; }
  __syncthreads();
  if (t == 0) {
    stats[n * 2]     = sm[0] + sm[1] + sm[2] + sm[3];
    stats[n * 2 + 1] = sm[4] + sm[5] + sm[6] + sm[7];
  }
}

// ---- GroupNorm apply + affine + relu (interior only) ----
__global__ __launch_bounds__(256) void gnapply2_kernel(
    unsigned short* __restrict__ x, const float* __restrict__ stats,
    const float* __restrict__ gamma, const float* __restrict__ beta) {
  int n = blockIdx.y, t = threadIdx.x;
  int c2 = t * 2;
  unsigned short* xb = x + (size_t)n * ACT_N;
  const float M = 512.f * 196.f;
  float mu = stats[n * 2] / M;
  float var = stats[n * 2 + 1] / M - mu * mu;
  float inv = rsqrtf(var + 1e-5f);
  float g0 = gamma[c2], g1 = gamma[c2 + 1];
  float be0 = beta[c2], be1 = beta[c2 + 1];
  for (int j = 0; j < 28; j++) {
    int i = blockIdx.x * 28 + j;
    int pp = (i / 14 + 1) * 16 + (i % 14) + 1;
    unsigned int vv = *(unsigned int*)(xb + pp * 512 + c2);
    float a = (b2f((unsigned short)vv) - mu) * inv * g0 + be0;
    float b = (b2f((unsigned short)(vv >> 16)) - mu) * inv * g1 + be1;
    a = fmaxf(a, 0.f); b = fmaxf(b, 0.f);
    *(unsigned int*)(xb + pp * 512 + c2) =
        (unsigned int)f2b(a) | ((unsigned int)f2b(b) << 16);
  }
}

// ---- final: mean over interior 196 -> out[n][1024+c] (f32) ----
__global__ void fmean2_kernel(const unsigned short* __restrict__ x, float* __restrict__ out) {
  int n = blockIdx.x, t = threadIdx.x;
  const unsigned short* xb = x + (size_t)n * ACT_N;
  float s0 = 0.f, s1 = 0.f;
  for (int i = 0; i < 196; i++) {
    int pp = (i / 14 + 1) * 16 + (i % 14) + 1;
    unsigned int vv = *(const unsigned int*)(xb + pp * 512 + t * 2);
    s0 += b2f((unsigned short)vv);
    s1 += b2f((unsigned short)(vv >> 16));
  }
  out[(size_t)n * 1536 + 1024 + t * 2]     = s0 * (1.f / 196.f);
  out[(size_t)n * 1536 + 1024 + t * 2 + 1] = s1 * (1.f / 196.f);
}

extern "C" void kernel_launch(void* const* d_in, const int* in_sizes, int n_in,
                              void* d_out, int out_size, void* d_ws, size_t ws_size,
                              hipStream_t stream) {
  const float* x     = (const float*)d_in[0];
  const float* feat  = (const float*)d_in[1];
  const int*   rois  = (const int*)d_in[2];
  const float* w1    = (const float*)d_in[3];
  const float* w2    = (const float*)d_in[4];
  const float* wq    = (const float*)d_in[5];
  const float* wk    = (const float*)d_in[6];
  const float* wv    = (const float*)d_in[7];
  const float* wm    = (const float*)d_in[8];
  const float* gamma = (const float*)d_in[9];
  const float* beta  = (const float*)d_in[10];
  float* out = (float*)d_out;

  // ---- workspace layout ----
  float* wsf   = (float*)d_ws;
  float* xp    = wsf;                // 32768
  float* bias1 = xp + 32768;         // 16384
  float* stats = bias1 + 16384;      // 64
  float* att   = stats + 64;         // 262144  ([qn][pp][kn] f32)
  unsigned short* ub    = (unsigned short*)(att + 262144);
  unsigned short* featT = ub;                    // 8*256*1024   = 2097152
  unsigned short* W1g   = featT + 2097152;       // 512*1024     = 524288
  unsigned short* Wg2   = W1g + 524288;          // 13*W3SZ      = 30670848
  unsigned short* bufq  = Wg2 + 30670848;        // 4194304 each, q/k/v contiguous
  unsigned short* bufk  = bufq + 4194304;
  unsigned short* bufv  = bufk + 4194304;
  unsigned short* bufx  = bufv + 4194304;

  // bufx border rows must be zero (only interior ever written by convs)
  hipMemsetAsync(bufx, 0, (size_t)4194304 * 2, stream);

  pool_max_kernel<<<8192, 256, 0, stream>>>(x, xp, out);
  bias1_kernel<<<4096, 256, 0, stream>>>(w1, xp, bias1);
  wprep3_kernel<<<dim3(16, 8, 13), 256, 0, stream>>>(w2, wq, wk, wv, wm, Wg2);
  w1prep_kernel<<<dim3(32, 8), 256, 0, stream>>>(w1, W1g);
  ftprep_kernel<<<dim3(4, 16, 8), 256, 0, stream>>>(feat, featT);

  // conv1: 1x1, K=1024, +bias1, relu, full 16x16 output -> bufq
  conv_mfma_kernel<1, 1024, 4, 4, 1, true, false, true, false>
      <<<dim3(8, 32), 256, 0, stream>>>(featT, rois, W1g, bias1, bufq);
  // conv2: valid 3x3 -> padded interior of bufx, relu
  conv_mfma_kernel<9, 512, 2, 4, 2, true, false, false, true>
      <<<dim3(16, 32), 128, 0, stream>>>(bufq, nullptr, Wg2, nullptr, bufx);

  for (int d = 0; d < 3; d++) {
    // q,k,v batched: O=1536 over contiguous blocked tensors / output buffers
    conv_mfma_kernel<9, 512, 4, 4, 1, false, false, false, true>
        <<<dim3(24, 32), 256, 0, stream>>>(bufx, nullptr,
            Wg2 + (size_t)(1 + 4 * d) * W3SZ, nullptr, bufq);
    att2_kernel<<<dim3(32, 32), 256, 0, stream>>>(bufq, bufk, att);
    softmax2_kernel<<<32, 256, 0, stream>>>(att);
    vf2_kernel<<<256, 256, 0, stream>>>(att, bufv, bufq);
    gnstats2_kernel<<<32, 256, 0, stream>>>(bufq, stats);
    gnapply2_kernel<<<dim3(7, 32), 256, 0, stream>>>(bufq, stats,
        gamma + d * 512, beta + d * 512);
    // wm conv + residual add into bufx
    conv_mfma_kernel<9, 512, 2, 4, 2, false, true, false, true>
        <<<dim3(16, 32), 128, 0, stream>>>(bufq, nullptr,
            Wg2 + (size_t)(4 + 4 * d) * W3SZ, nullptr, bufx);
  }

  fmean2_kernel<<<32, 256, 0, stream>>>(bufx, out);
}

// Round 7
// 917.614 us; speedup vs baseline: 1.0390x; 1.0390x over previous
//
#include <hip/hip_runtime.h>

// ---------------------------------------------------------------------------
// ACARHead forward, bf16-MFMA convs, tap-group phases with DEPTH-2 COUNTED
// vmcnt pipeline (T3+T4): loads for phase f+2 issued at phase f; before
// compute(f) wait vmcnt(C) with C = exact in-flight count for f+1,f+2.
// Never drains vmcnt to 0 in the main loop.
// W rotates through 3 buffers (buffer = g), X double-buffered per K-step.
// Activation layout: bf16 [n][p=256][c]; 14x14 payload at rows/cols 1..14.
// ---------------------------------------------------------------------------

typedef __attribute__((ext_vector_type(8))) short bhalf8;
typedef __attribute__((ext_vector_type(4))) float floatx4;

#define ACT_N 131072   // 256*512 bf16 elements per sample
#define W3SZ  2359296  // 512*512*9 (also = blocked per-tensor short count)

__device__ inline float b2f(unsigned short u) {
  union { unsigned int i; float f; } x; x.i = ((unsigned int)u) << 16; return x.f;
}
__device__ inline unsigned short f2b(float f) {
  union { float f; unsigned int i; } x; x.f = f;
  return (unsigned short)((x.i + 0x7FFFu + ((x.i >> 16) & 1u)) >> 16);
}
__device__ inline void gload_lds16(const unsigned short* g, bhalf8* l) {
  __builtin_amdgcn_global_load_lds(
      (const __attribute__((address_space(1))) unsigned int*)(const void*)g,
      (__attribute__((address_space(3))) unsigned int*)(void*)l, 16, 0, 0);
}
template <int N> __device__ inline void waitvm() {
  asm volatile("s_waitcnt vmcnt(%0)" :: "i"(N) : "memory");
}
__device__ inline void phase_barrier_pre() {   // after issues, before compute
  __builtin_amdgcn_sched_barrier(0);
  __builtin_amdgcn_s_barrier();
  __builtin_amdgcn_sched_barrier(0);
}
__device__ inline void phase_barrier_post() {  // after compute
  __builtin_amdgcn_sched_barrier(0);
  __builtin_amdgcn_s_barrier();
  __builtin_amdgcn_sched_barrier(0);
}

// ---- AdaptiveMaxPool3d(1): max over 196, write xp (f32) and out[:,0:1024] ----
__global__ void pool_max_kernel(const float* __restrict__ x, float* __restrict__ xp,
                                float* __restrict__ out) {
  int tid = threadIdx.x;
  int wid = blockIdx.x * 4 + (tid >> 6);   // n*1024 + c
  int lane = tid & 63;
  int n = wid >> 10, c = wid & 1023;
  const float* p = x + (size_t)wid * 196;
  float v = -3.4e38f;
  v = fmaxf(v, p[lane]);
  v = fmaxf(v, p[lane + 64]);
  v = fmaxf(v, p[lane + 128]);
  if (lane < 4) v = fmaxf(v, p[lane + 192]);
#pragma unroll
  for (int off = 32; off >= 1; off >>= 1) v = fmaxf(v, __shfl_xor(v, off));
  if (lane == 0) { xp[wid] = v; out[(size_t)n * 1536 + c] = v; }
}

// ---- bias1[n][o] = sum_{c<1024} w1[o][1024+c] * xp[n][c]  (f32) ----
__global__ void bias1_kernel(const float* __restrict__ w1, const float* __restrict__ xp,
                             float* __restrict__ bias1) {
  int tid = threadIdx.x;
  int wid = blockIdx.x * 4 + (tid >> 6);   // n*512 + o
  int lane = tid & 63;
  int n = wid >> 9, o = wid & 511;
  const float* wr = w1 + (size_t)o * 2048 + 1024;
  const float* xr = xp + (size_t)n * 1024;
  float s = 0.f;
#pragma unroll
  for (int r = 0; r < 16; r++) { int c = lane + r * 64; s += wr[c] * xr[c]; }
#pragma unroll
  for (int off = 32; off >= 1; off >>= 1) s += __shfl_xor(s, off);
  if (lane == 0) bias1[wid] = s;
}

// ---- 3x3 weight prep -> tap-grouped blocked layout ----
// Wg2[tensor][ot(8)][ks(16)][slot u(2304)][8 bf16]:
//   u = g*768 + (dh*4+kg)*64 + o ; data = w[o0+o][ks*32+kg*8+j][dh*3+g]
__global__ __launch_bounds__(256) void wprep3_kernel(
    const float* __restrict__ w2, const float* __restrict__ wq,
    const float* __restrict__ wk, const float* __restrict__ wv,
    const float* __restrict__ wm, unsigned short* __restrict__ Wg2) {
  int ks = blockIdx.x, ot = blockIdx.y, tid = blockIdx.z;
  int t = threadIdx.x;
  const float* src;
  if (tid == 0) src = w2;
  else {
    int d = (tid - 1) >> 2, r = (tid - 1) & 3;
    src = (r == 0 ? wq : r == 1 ? wk : r == 2 ? wv : wm) + (size_t)d * W3SZ;
  }
  __shared__ unsigned short S[64 * 288];
  const float* sb = src + (size_t)ot * 64 * 4608 + (size_t)ks * 288;
  for (int j = 0; j < 72; j++) {
    int flat = j * 256 + t;          // < 18432
    int o = flat / 288, ci = flat % 288;
    S[flat] = f2b(sb[(size_t)o * 4608 + ci]);
  }
  __syncthreads();
  unsigned short* dst = Wg2 + (((size_t)(tid * 8 + ot) * 16 + ks) * 2304) * 8;
#pragma unroll
  for (int s = 0; s < 9; s++) {
    int u = t + s * 256;
    int g = u / 768, rem = u % 768;
    int rl = rem >> 6, o = rem & 63;
    int dh = rl >> 2, kg = rl & 3;
    int t9src = dh * 3 + g;
    bhalf8 v;
#pragma unroll
    for (int j = 0; j < 8; j++) v[j] = (short)S[o * 288 + (kg * 8 + j) * 9 + t9src];
    *(bhalf8*)(dst + (size_t)u * 8) = v;
  }
}

// ---- conv1 weight prep -> blocked: W1g[ot(8)][ks(32)][slot(256)][8] ----
__global__ void w1prep_kernel(const float* __restrict__ w1, unsigned short* __restrict__ W1g) {
  int ks = blockIdx.x, ot = blockIdx.y, t = threadIdx.x;
  int kg = t >> 6, o = t & 63;
  const float* s = w1 + (size_t)(ot * 64 + o) * 2048 + ks * 32 + kg * 8;
  bhalf8 v;
#pragma unroll
  for (int j = 0; j < 8; j++) v[j] = (short)f2b(s[j]);
  *(bhalf8*)(W1g + (((size_t)ot * 32 + ks) * 256 + t) * 8) = v;
}

// ---- feat transpose: feat[img][c][p] f32 -> featT[img][p][c] bf16 ----
__global__ __launch_bounds__(256) void ftprep_kernel(
    const float* __restrict__ feat, unsigned short* __restrict__ featT) {
  int img = blockIdx.z, c0 = blockIdx.y * 64, p0 = blockIdx.x * 64;
  int t = threadIdx.x;
  int a = t >> 6, b = t & 63;
  __shared__ float S[64][65];
#pragma unroll
  for (int j = 0; j < 16; j++) {
    int r = a * 16 + j;
    S[r][b] = feat[((size_t)img * 1024 + c0 + r) * 256 + p0 + b];
  }
  __syncthreads();
#pragma unroll
  for (int j = 0; j < 16; j++) {
    int pl = a * 16 + j;
    featT[((size_t)img * 256 + p0 + pl) * 1024 + c0 + b] = f2b(S[b][pl]);
  }
}

// ---------------------------------------------------------------------------
// Unified MFMA conv, depth-2 counted-vmcnt pipeline.
// Block tile 64o x (256/PSPLIT)p; per-wave 64o x (NREP*16)p.
// ---------------------------------------------------------------------------
template <int TAPS, int KTOT, int WAVES, int NREP, int PSPLIT,
          bool RELU, bool ADD, bool BIAS, bool VALID>
__global__ __launch_bounds__(WAVES * 64) void conv_mfma_kernel(
    const unsigned short* __restrict__ Xg, const int* __restrict__ rois,
    const unsigned short* __restrict__ Wg, const float* __restrict__ bias,
    unsigned short* __restrict__ Out) {
  constexpr int THREADS = WAVES * 64;
  constexpr int NK = KTOT / 32;
  static_assert(PSPLIT * WAVES * NREP * 16 == 256, "p coverage");

  int n = blockIdx.y;
  int ot = blockIdx.x / PSPLIT;
  int pq = blockIdx.x % PSPLIT;
  int t = threadIdx.x;
  int wv = t >> 6, l = t & 63, l15 = l & 15, l4 = l >> 4;
  int pbase = (pq * WAVES + wv) * (NREP * 16);
  const unsigned short* xb =
      Xg + (rois ? (size_t)rois[n * 5] * 256 * KTOT : (size_t)n * 256 * KTOT);
  floatx4 acc[4][NREP] = {};

  if constexpr (TAPS == 9) {
    constexpr int LW = 768 / THREADS;    // W gloads per thread per phase
    constexpr int LX = 1024 / THREADS;   // X gloads per thread per K-step
    static_assert(768 % THREADS == 0 && 1024 % THREADS == 0, "stage div");
    __shared__ bhalf8 Xs[2][1024];
    __shared__ bhalf8 Wl[3][768];

    auto stageX = [&](int xbuf, int ks) {
#pragma unroll
      for (int i = 0; i < LX; i++) {
        int base = i * THREADS + wv * 64;
        int u = base + l;
        int p = u & 255, kg = u >> 8;
        gload_lds16(xb + (size_t)p * KTOT + ks * 32 + kg * 8, &Xs[xbuf][base]);
      }
    };
    auto stageW = [&](int wbuf, int ks, int g) {
      const unsigned short* wb =
          Wg + (((size_t)ot * NK + ks) * 2304 + g * 768) * 8;
#pragma unroll
      for (int i = 0; i < LW; i++) {
        int base = i * THREADS + wv * 64;
        gload_lds16(wb + (size_t)(base + l) * 8, &Wl[wbuf][base]);
      }
    };
    auto computeG = [&](const bhalf8* X, const bhalf8* W, int g) {
      bhalf8 BW[NREP + 2];
#pragma unroll
      for (int w10 = 0; w10 < NREP + 2; w10++) {
        int row = (pbase + w10 * 16 + l15 + g) & 255;
        BW[w10] = X[l4 * 256 + row];
      }
#pragma unroll
      for (int dh = 0; dh < 3; dh++) {
        bhalf8 A[4];
#pragma unroll
        for (int of = 0; of < 4; of++) A[of] = W[(dh * 4 + l4) * 64 + of * 16 + l15];
#pragma unroll
        for (int of = 0; of < 4; of++)
#pragma unroll
          for (int pf = 0; pf < NREP; pf++)
            acc[of][pf] = __builtin_amdgcn_mfma_f32_16x16x32_bf16(
                A[of], BW[pf + dh], acc[of][pf], 0, 0, 0);
      }
    };

    // prologue: loads for phase (0,0) and (0,1)
    stageW(0, 0, 0); stageX(0, 0);
    stageW(1, 0, 1);

    for (int ks = 0; ks < NK - 1; ks++) {
      const bhalf8* X = Xs[ks & 1];
      // phase (ks,0): issue (ks,2) -> buf2 ; allowed in flight: (ks,1)+(ks,2)
      stageW(2, ks, 2);
      waitvm<2 * LW>();
      phase_barrier_pre();
      computeG(X, Wl[0], 0);
      phase_barrier_post();
      // phase (ks,1): issue (ks+1,0) -> buf0 + X(ks+1)
      stageW(0, ks + 1, 0); stageX((ks + 1) & 1, ks + 1);
      waitvm<2 * LW + LX>();
      phase_barrier_pre();
      computeG(X, Wl[1], 1);
      phase_barrier_post();
      // phase (ks,2): issue (ks+1,1) -> buf1
      stageW(1, ks + 1, 1);
      waitvm<2 * LW + LX>();
      phase_barrier_pre();
      computeG(X, Wl[2], 2);
      phase_barrier_post();
    }
    {  // peeled last K-step (exact tail counts)
      const bhalf8* X = Xs[(NK - 1) & 1];
      stageW(2, NK - 1, 2);
      waitvm<2 * LW>();
      phase_barrier_pre();
      computeG(X, Wl[0], 0);
      phase_barrier_post();
      waitvm<LW>();
      phase_barrier_pre();
      computeG(X, Wl[1], 1);
      phase_barrier_post();
      waitvm<0>();
      phase_barrier_pre();
      computeG(X, Wl[2], 2);
      phase_barrier_post();
    }
  } else {
    constexpr int LW = 256 / THREADS;
    constexpr int LX = 1024 / THREADS;
    static_assert(256 % THREADS == 0 && 1024 % THREADS == 0, "stage div");
    __shared__ bhalf8 Xs[3][1024];
    __shared__ bhalf8 Wl[3][256];

    auto stage1 = [&](int b, int ks) {
#pragma unroll
      for (int i = 0; i < LX; i++) {
        int base = i * THREADS + wv * 64;
        int u = base + l;
        int p = u & 255, kg = u >> 8;
        gload_lds16(xb + (size_t)p * KTOT + ks * 32 + kg * 8, &Xs[b][base]);
      }
      const unsigned short* wb = Wg + (((size_t)ot * NK + ks) * 256) * 8;
#pragma unroll
      for (int i = 0; i < LW; i++) {
        int base = i * THREADS + wv * 64;
        gload_lds16(wb + (size_t)(base + l) * 8, &Wl[b][base]);
      }
    };
    auto compute1 = [&](const bhalf8* X, const bhalf8* W) {
      bhalf8 B[NREP];
#pragma unroll
      for (int pf = 0; pf < NREP; pf++) {
        int row = (pbase + pf * 16 + l15) & 255;
        B[pf] = X[l4 * 256 + row];
      }
#pragma unroll
      for (int of = 0; of < 4; of++) {
        bhalf8 A = W[l4 * 64 + of * 16 + l15];
#pragma unroll
        for (int pf = 0; pf < NREP; pf++)
          acc[of][pf] = __builtin_amdgcn_mfma_f32_16x16x32_bf16(
              A, B[pf], acc[of][pf], 0, 0, 0);
      }
    };

    stage1(0, 0);
    stage1(1, 1);
    int b = 0;
    for (int ks = 0; ks < NK - 2; ks++) {
      int b2 = b + 2; if (b2 >= 3) b2 -= 3;
      stage1(b2, ks + 2);
      waitvm<2 * (LW + LX)>();
      phase_barrier_pre();
      compute1(Xs[b], Wl[b]);
      phase_barrier_post();
      b = b + 1; if (b >= 3) b -= 3;
    }
    // peeled: ks = NK-2, NK-1
    waitvm<LW + LX>();
    phase_barrier_pre();
    compute1(Xs[b], Wl[b]);
    phase_barrier_post();
    b = b + 1; if (b >= 3) b -= 3;
    waitvm<0>();
    phase_barrier_pre();
    compute1(Xs[b], Wl[b]);
    phase_barrier_post();
  }

#pragma unroll
  for (int of = 0; of < 4; of++) {
    int og = ot * 64 + of * 16 + l4 * 4;
    int tensor = og >> 9, ol = og & 511;
#pragma unroll
    for (int pf = 0; pf < NREP; pf++) {
      int p = pbase + pf * 16 + l15;
      int po = p;
      if (VALID) {
        int h = p >> 4, w = p & 15;
        if (h >= 14 || w >= 14) continue;
        po = (h + 1) * 16 + (w + 1);
      }
      unsigned short* dp = Out + (((size_t)tensor * 32 + n) * 256 + po) * 512 + ol;
      float vv[4];
#pragma unroll
      for (int r2 = 0; r2 < 4; r2++) vv[r2] = acc[of][pf][r2];
      if (BIAS) {
#pragma unroll
        for (int r2 = 0; r2 < 4; r2++) vv[r2] += bias[(size_t)n * 512 + ol + r2];
      }
      if (ADD) {
        ushort4 old = *(const ushort4*)dp;
        vv[0] += b2f(old.x); vv[1] += b2f(old.y); vv[2] += b2f(old.z); vv[3] += b2f(old.w);
      }
      if (RELU) {
#pragma unroll
        for (int r2 = 0; r2 < 4; r2++) vv[r2] = fmaxf(vv[r2], 0.f);
      }
      ushort4 st = { f2b(vv[0]), f2b(vv[1]), f2b(vv[2]), f2b(vv[3]) };
      *(ushort4*)dp = st;
    }
  }
}

// ---- att[qn][pp][kn] = (1/sqrt(512)) * sum_c q[qn][pp][c]*k[kn][pp][c] ----
__global__ __launch_bounds__(256) void att2_kernel(
    const unsigned short* __restrict__ q, const unsigned short* __restrict__ k,
    float* __restrict__ att) {
  int kn = blockIdx.x, qn = blockIdx.y;
  int t = threadIdx.x, wv = t >> 6, l = t & 63;
  const unsigned short* qb = q + (size_t)qn * ACT_N;
  const unsigned short* kb = k + (size_t)kn * ACT_N;
  for (int i = wv; i < 196; i += 4) {
    int pp = (i / 14 + 1) * 16 + (i % 14) + 1;
    bhalf8 qv = *(const bhalf8*)(qb + pp * 512 + l * 8);
    bhalf8 kv = *(const bhalf8*)(kb + pp * 512 + l * 8);
    float s = 0.f;
#pragma unroll
    for (int j = 0; j < 8; j++)
      s += b2f((unsigned short)qv[j]) * b2f((unsigned short)kv[j]);
#pragma unroll
    for (int off = 32; off >= 1; off >>= 1) s += __shfl_xor(s, off);
    if (l == 0) att[((size_t)qn * 256 + pp) * 32 + kn] = s * 0.044194173824159216f;
  }
}

// ---- softmax over kn (32 contiguous f32 per (qn,pp)) ----
__global__ void softmax2_kernel(float* __restrict__ att) {
  int qn = blockIdx.x, t = threadIdx.x;
  if (t >= 196) return;
  int pp = (t / 14 + 1) * 16 + (t % 14) + 1;
  float* a = att + ((size_t)qn * 256 + pp) * 32;
  float v[32]; float m = -3.4e38f;
#pragma unroll
  for (int i = 0; i < 32; i++) { v[i] = a[i]; m = fmaxf(m, v[i]); }
  float s = 0.f;
#pragma unroll
  for (int i = 0; i < 32; i++) { v[i] = __expf(v[i] - m); s += v[i]; }
  float inv = 1.f / s;
#pragma unroll
  for (int i = 0; i < 32; i++) a[i] = v[i] * inv;
}

// ---- vf[qn][p][c] = sum_kn att[qn][p][kn]*v[kn][p][c]; border rows -> 0 ----
__global__ __launch_bounds__(256) void vf2_kernel(
    const float* __restrict__ att, const unsigned short* __restrict__ v,
    unsigned short* __restrict__ o) {
  int p = blockIdx.x, t = threadIdx.x;
  int h = p >> 4, w = p & 15;
  if (h < 1 || h > 14 || w < 1 || w > 14) {
    for (int qn = 0; qn < 32; qn++)
      *(unsigned int*)(o + ((size_t)qn * 256 + p) * 512 + t * 2) = 0u;
    return;
  }
  __shared__ float attS[1024];
  __shared__ unsigned short vS[32 * 512];
#pragma unroll
  for (int i = 0; i < 4; i++) {
    int idx = t + i * 256;
    int qn = idx >> 5, kn = idx & 31;
    attS[idx] = att[((size_t)qn * 256 + p) * 32 + kn];
  }
#pragma unroll
  for (int i = 0; i < 8; i++) {
    int u = t + i * 256;
    int kn = u >> 6, cu = (u & 63) * 8;
    *(bhalf8*)&vS[kn * 512 + cu] = *(const bhalf8*)(v + ((size_t)kn * 256 + p) * 512 + cu);
  }
  __syncthreads();
  int c2 = t * 2;
  for (int qn = 0; qn < 32; qn++) {
    float s0 = 0.f, s1 = 0.f;
#pragma unroll
    for (int kn = 0; kn < 32; kn++) {
      float a = attS[qn * 32 + kn];
      unsigned int vv = *(const unsigned int*)&vS[kn * 512 + c2];
      s0 += a * b2f((unsigned short)vv);
      s1 += a * b2f((unsigned short)(vv >> 16));
    }
    unsigned int pkd = (unsigned int)f2b(s0) | ((unsigned int)f2b(s1) << 16);
    *(unsigned int*)(o + ((size_t)qn * 256 + p) * 512 + c2) = pkd;
  }
}

// ---- GroupNorm stats over interior (196 x 512) per n ----
__global__ __launch_bounds__(256) void gnstats2_kernel(
    const unsigned short* __restrict__ x, float* __restrict__ stats) {
  int n = blockIdx.x, t = threadIdx.x;
  const unsigned short* xb = x + (size_t)n * ACT_N;
  float s = 0.f, ss = 0.f;
  for (int i = 0; i < 196; i++) {
    int pp = (i / 14 + 1) * 16 + (i % 14) + 1;
    unsigned int vv = *(const unsigned int*)(xb + pp * 512 + t * 2);
    float a = b2f((unsigned short)vv), b = b2f((unsigned short)(vv >> 16));
    s += a + b; ss += a * a + b * b;
  }
#pragma unroll
  for (int off = 32; off >= 1; off >>= 1) { s += __shfl_xor(s, off); ss += __shfl_xor(ss, off); }
  __shared__ float sm[8];
  int wv = t >> 6, ln = t & 63;
  if (ln == 0) { sm[wv] = s; sm[4 + wv] = ss; }
  __syncthreads();
  if (t == 0) {
    stats[n * 2]     = sm[0] + sm[1] + sm[2] + sm[3];
    stats[n * 2 + 1] = sm[4] + sm[5] + sm[6] + sm[7];
  }
}

// ---- GroupNorm apply + affine + relu (interior only) ----
__global__ __launch_bounds__(256) void gnapply2_kernel(
    unsigned short* __restrict__ x, const float* __restrict__ stats,
    const float* __restrict__ gamma, const float* __restrict__ beta) {
  int n = blockIdx.y, t = threadIdx.x;
  int c2 = t * 2;
  unsigned short* xb = x + (size_t)n * ACT_N;
  const float M = 512.f * 196.f;
  float mu = stats[n * 2] / M;
  float var = stats[n * 2 + 1] / M - mu * mu;
  float inv = rsqrtf(var + 1e-5f);
  float g0 = gamma[c2], g1 = gamma[c2 + 1];
  float be0 = beta[c2], be1 = beta[c2 + 1];
  for (int j = 0; j < 28; j++) {
    int i = blockIdx.x * 28 + j;
    int pp = (i / 14 + 1) * 16 + (i % 14) + 1;
    unsigned int vv = *(unsigned int*)(xb + pp * 512 + c2);
    float a = (b2f((unsigned short)vv) - mu) * inv * g0 + be0;
    float b = (b2f((unsigned short)(vv >> 16)) - mu) * inv * g1 + be1;
    a = fmaxf(a, 0.f); b = fmaxf(b, 0.f);
    *(unsigned int*)(xb + pp * 512 + c2) =
        (unsigned int)f2b(a) | ((unsigned int)f2b(b) << 16);
  }
}

// ---- final: mean over interior 196 -> out[n][1024+c] (f32) ----
__global__ void fmean2_kernel(const unsigned short* __restrict__ x, float* __restrict__ out) {
  int n = blockIdx.x, t = threadIdx.x;
  const unsigned short* xb = x + (size_t)n * ACT_N;
  float s0 = 0.f, s1 = 0.f;
  for (int i = 0; i < 196; i++) {
    int pp = (i / 14 + 1) * 16 + (i % 14) + 1;
    unsigned int vv = *(const unsigned int*)(xb + pp * 512 + t * 2);
    s0 += b2f((unsigned short)vv);
    s1 += b2f((unsigned short)(vv >> 16));
  }
  out[(size_t)n * 1536 + 1024 + t * 2]     = s0 * (1.f / 196.f);
  out[(size_t)n * 1536 + 1024 + t * 2 + 1] = s1 * (1.f / 196.f);
}

extern "C" void kernel_launch(void* const* d_in, const int* in_sizes, int n_in,
                              void* d_out, int out_size, void* d_ws, size_t ws_size,
                              hipStream_t stream) {
  const float* x     = (const float*)d_in[0];
  const float* feat  = (const float*)d_in[1];
  const int*   rois  = (const int*)d_in[2];
  const float* w1    = (const float*)d_in[3];
  const float* w2    = (const float*)d_in[4];
  const float* wq    = (const float*)d_in[5];
  const float* wk    = (const float*)d_in[6];
  const float* wv    = (const float*)d_in[7];
  const float* wm    = (const float*)d_in[8];
  const float* gamma = (const float*)d_in[9];
  const float* beta  = (const float*)d_in[10];
  float* out = (float*)d_out;

  // ---- workspace layout ----
  float* wsf   = (float*)d_ws;
  float* xp    = wsf;                // 32768
  float* bias1 = xp + 32768;         // 16384
  float* stats = bias1 + 16384;      // 64
  float* att   = stats + 64;         // 262144  ([qn][pp][kn] f32)
  unsigned short* ub    = (unsigned short*)(att + 262144);
  unsigned short* featT = ub;                    // 8*256*1024   = 2097152
  unsigned short* W1g   = featT + 2097152;       // 512*1024     = 524288
  unsigned short* Wg2   = W1g + 524288;          // 13*W3SZ      = 30670848
  unsigned short* bufq  = Wg2 + 30670848;        // 4194304 each, q/k/v contiguous
  unsigned short* bufk  = bufq + 4194304;
  unsigned short* bufv  = bufk + 4194304;
  unsigned short* bufx  = bufv + 4194304;

  // bufx border rows must be zero (only interior ever written by convs)
  hipMemsetAsync(bufx, 0, (size_t)4194304 * 2, stream);

  pool_max_kernel<<<8192, 256, 0, stream>>>(x, xp, out);
  bias1_kernel<<<4096, 256, 0, stream>>>(w1, xp, bias1);
  wprep3_kernel<<<dim3(16, 8, 13), 256, 0, stream>>>(w2, wq, wk, wv, wm, Wg2);
  w1prep_kernel<<<dim3(32, 8), 256, 0, stream>>>(w1, W1g);
  ftprep_kernel<<<dim3(4, 16, 8), 256, 0, stream>>>(feat, featT);

  // conv1: 1x1, K=1024, +bias1, relu, full 16x16 output -> bufq
  conv_mfma_kernel<1, 1024, 4, 4, 1, true, false, true, false>
      <<<dim3(8, 32), 256, 0, stream>>>(featT, rois, W1g, bias1, bufq);
  // conv2: valid 3x3 -> padded interior of bufx, relu
  conv_mfma_kernel<9, 512, 2, 4, 2, true, false, false, true>
      <<<dim3(16, 32), 128, 0, stream>>>(bufq, nullptr, Wg2, nullptr, bufx);

  for (int d = 0; d < 3; d++) {
    // q,k,v batched: O=1536 over contiguous blocked tensors / output buffers
    conv_mfma_kernel<9, 512, 4, 4, 1, false, false, false, true>
        <<<dim3(24, 32), 256, 0, stream>>>(bufx, nullptr,
            Wg2 + (size_t)(1 + 4 * d) * W3SZ, nullptr, bufq);
    att2_kernel<<<dim3(32, 32), 256, 0, stream>>>(bufq, bufk, att);
    softmax2_kernel<<<32, 256, 0, stream>>>(att);
    vf2_kernel<<<256, 256, 0, stream>>>(att, bufv, bufq);
    gnstats2_kernel<<<32, 256, 0, stream>>>(bufq, stats);
    gnapply2_kernel<<<dim3(7, 32), 256, 0, stream>>>(bufq, stats,
        gamma + d * 512, beta + d * 512);
    // wm conv + residual add into bufx
    conv_mfma_kernel<9, 512, 2, 4, 2, false, true, false, true>
        <<<dim3(16, 32), 128, 0, stream>>>(bufq, nullptr,
            Wg2 + (size_t)(4 + 4 * d) * W3SZ, nullptr, bufx);
  }

  fmean2_kernel<<<32, 256, 0, stream>>>(bufx, out);
}

// Round 8
// 887.147 us; speedup vs baseline: 1.0747x; 1.0343x over previous
//
#include <hip/hip_runtime.h>

// ---------------------------------------------------------------------------
// ACARHead forward, bf16-MFMA convs, tap-group phases with DEPTH-2 COUNTED
// vmcnt pipeline (T3+T4) + s_setprio MFMA clusters (T5).
// W rotates through 3 buffers (buffer = g), X double-buffered per K-step.
// Activation layout: bf16 [n][p=256][c]; 14x14 payload at rows/cols 1..14.
// ---------------------------------------------------------------------------

typedef __attribute__((ext_vector_type(8))) short bhalf8;
typedef __attribute__((ext_vector_type(4))) float floatx4;

#define ACT_N 131072   // 256*512 bf16 elements per sample
#define W3SZ  2359296  // 512*512*9 (also = blocked per-tensor short count)

__device__ inline float b2f(unsigned short u) {
  union { unsigned int i; float f; } x; x.i = ((unsigned int)u) << 16; return x.f;
}
__device__ inline unsigned short f2b(float f) {
  union { float f; unsigned int i; } x; x.f = f;
  return (unsigned short)((x.i + 0x7FFFu + ((x.i >> 16) & 1u)) >> 16);
}
__device__ inline void gload_lds16(const unsigned short* g, bhalf8* l) {
  __builtin_amdgcn_global_load_lds(
      (const __attribute__((address_space(1))) unsigned int*)(const void*)g,
      (__attribute__((address_space(3))) unsigned int*)(void*)l, 16, 0, 0);
}
template <int N> __device__ inline void waitvm() {
  asm volatile("s_waitcnt vmcnt(%0)" :: "i"(N) : "memory");
}
__device__ inline void phase_barrier_pre() {   // after issues, before compute
  __builtin_amdgcn_sched_barrier(0);
  __builtin_amdgcn_s_barrier();
  __builtin_amdgcn_sched_barrier(0);
}
__device__ inline void phase_barrier_post() {  // after compute
  __builtin_amdgcn_sched_barrier(0);
  __builtin_amdgcn_s_barrier();
  __builtin_amdgcn_sched_barrier(0);
}

// ---- AdaptiveMaxPool3d(1): max over 196, write xp (f32) and out[:,0:1024] ----
__global__ void pool_max_kernel(const float* __restrict__ x, float* __restrict__ xp,
                                float* __restrict__ out) {
  int tid = threadIdx.x;
  int wid = blockIdx.x * 4 + (tid >> 6);   // n*1024 + c
  int lane = tid & 63;
  int n = wid >> 10, c = wid & 1023;
  const float* p = x + (size_t)wid * 196;
  float v = -3.4e38f;
  v = fmaxf(v, p[lane]);
  v = fmaxf(v, p[lane + 64]);
  v = fmaxf(v, p[lane + 128]);
  if (lane < 4) v = fmaxf(v, p[lane + 192]);
#pragma unroll
  for (int off = 32; off >= 1; off >>= 1) v = fmaxf(v, __shfl_xor(v, off));
  if (lane == 0) { xp[wid] = v; out[(size_t)n * 1536 + c] = v; }
}

// ---- bias1[n][o] = sum_{c<1024} w1[o][1024+c] * xp[n][c]  (f32) ----
__global__ void bias1_kernel(const float* __restrict__ w1, const float* __restrict__ xp,
                             float* __restrict__ bias1) {
  int tid = threadIdx.x;
  int wid = blockIdx.x * 4 + (tid >> 6);   // n*512 + o
  int lane = tid & 63;
  int n = wid >> 9, o = wid & 511;
  const float* wr = w1 + (size_t)o * 2048 + 1024;
  const float* xr = xp + (size_t)n * 1024;
  float s = 0.f;
#pragma unroll
  for (int r = 0; r < 16; r++) { int c = lane + r * 64; s += wr[c] * xr[c]; }
#pragma unroll
  for (int off = 32; off >= 1; off >>= 1) s += __shfl_xor(s, off);
  if (lane == 0) bias1[wid] = s;
}

// ---- 3x3 weight prep -> tap-grouped blocked layout ----
// Wg2[tensor][ot(8)][ks(16)][slot u(2304)][8 bf16]:
//   u = g*768 + (dh*4+kg)*64 + o ; data = w[o0+o][ks*32+kg*8+j][dh*3+g]
__global__ __launch_bounds__(256) void wprep3_kernel(
    const float* __restrict__ w2, const float* __restrict__ wq,
    const float* __restrict__ wk, const float* __restrict__ wv,
    const float* __restrict__ wm, unsigned short* __restrict__ Wg2) {
  int ks = blockIdx.x, ot = blockIdx.y, tid = blockIdx.z;
  int t = threadIdx.x;
  const float* src;
  if (tid == 0) src = w2;
  else {
    int d = (tid - 1) >> 2, r = (tid - 1) & 3;
    src = (r == 0 ? wq : r == 1 ? wk : r == 2 ? wv : wm) + (size_t)d * W3SZ;
  }
  __shared__ unsigned short S[64 * 288];
  const float* sb = src + (size_t)ot * 64 * 4608 + (size_t)ks * 288;
  for (int j = 0; j < 72; j++) {
    int flat = j * 256 + t;          // < 18432
    int o = flat / 288, ci = flat % 288;
    S[flat] = f2b(sb[(size_t)o * 4608 + ci]);
  }
  __syncthreads();
  unsigned short* dst = Wg2 + (((size_t)(tid * 8 + ot) * 16 + ks) * 2304) * 8;
#pragma unroll
  for (int s = 0; s < 9; s++) {
    int u = t + s * 256;
    int g = u / 768, rem = u % 768;
    int rl = rem >> 6, o = rem & 63;
    int dh = rl >> 2, kg = rl & 3;
    int t9src = dh * 3 + g;
    bhalf8 v;
#pragma unroll
    for (int j = 0; j < 8; j++) v[j] = (short)S[o * 288 + (kg * 8 + j) * 9 + t9src];
    *(bhalf8*)(dst + (size_t)u * 8) = v;
  }
}

// ---- conv1 weight prep -> blocked: W1g[ot(8)][ks(32)][slot(256)][8] ----
__global__ void w1prep_kernel(const float* __restrict__ w1, unsigned short* __restrict__ W1g) {
  int ks = blockIdx.x, ot = blockIdx.y, t = threadIdx.x;
  int kg = t >> 6, o = t & 63;
  const float* s = w1 + (size_t)(ot * 64 + o) * 2048 + ks * 32 + kg * 8;
  bhalf8 v;
#pragma unroll
  for (int j = 0; j < 8; j++) v[j] = (short)f2b(s[j]);
  *(bhalf8*)(W1g + (((size_t)ot * 32 + ks) * 256 + t) * 8) = v;
}

// ---- feat transpose: feat[img][c][p] f32 -> featT[img][p][c] bf16 ----
__global__ __launch_bounds__(256) void ftprep_kernel(
    const float* __restrict__ feat, unsigned short* __restrict__ featT) {
  int img = blockIdx.z, c0 = blockIdx.y * 64, p0 = blockIdx.x * 64;
  int t = threadIdx.x;
  int a = t >> 6, b = t & 63;
  __shared__ float S[64][65];
#pragma unroll
  for (int j = 0; j < 16; j++) {
    int r = a * 16 + j;
    S[r][b] = feat[((size_t)img * 1024 + c0 + r) * 256 + p0 + b];
  }
  __syncthreads();
#pragma unroll
  for (int j = 0; j < 16; j++) {
    int pl = a * 16 + j;
    featT[((size_t)img * 256 + p0 + pl) * 1024 + c0 + b] = f2b(S[b][pl]);
  }
}

// ---------------------------------------------------------------------------
// Unified MFMA conv, depth-2 counted-vmcnt pipeline + setprio MFMA clusters.
// Block tile 64o x (256/PSPLIT)p; per-wave 64o x (NREP*16)p.
// ---------------------------------------------------------------------------
template <int TAPS, int KTOT, int WAVES, int NREP, int PSPLIT,
          bool RELU, bool ADD, bool BIAS, bool VALID>
__global__ __launch_bounds__(WAVES * 64) void conv_mfma_kernel(
    const unsigned short* __restrict__ Xg, const int* __restrict__ rois,
    const unsigned short* __restrict__ Wg, const float* __restrict__ bias,
    unsigned short* __restrict__ Out) {
  constexpr int THREADS = WAVES * 64;
  constexpr int NK = KTOT / 32;
  static_assert(PSPLIT * WAVES * NREP * 16 == 256, "p coverage");

  int n = blockIdx.y;
  int ot = blockIdx.x / PSPLIT;
  int pq = blockIdx.x % PSPLIT;
  int t = threadIdx.x;
  int wv = t >> 6, l = t & 63, l15 = l & 15, l4 = l >> 4;
  int pbase = (pq * WAVES + wv) * (NREP * 16);
  const unsigned short* xb =
      Xg + (rois ? (size_t)rois[n * 5] * 256 * KTOT : (size_t)n * 256 * KTOT);
  floatx4 acc[4][NREP] = {};

  if constexpr (TAPS == 9) {
    constexpr int LW = 768 / THREADS;    // W gloads per thread per phase
    constexpr int LX = 1024 / THREADS;   // X gloads per thread per K-step
    static_assert(768 % THREADS == 0 && 1024 % THREADS == 0, "stage div");
    __shared__ bhalf8 Xs[2][1024];
    __shared__ bhalf8 Wl[3][768];

    auto stageX = [&](int xbuf, int ks) {
#pragma unroll
      for (int i = 0; i < LX; i++) {
        int base = i * THREADS + wv * 64;
        int u = base + l;
        int p = u & 255, kg = u >> 8;
        gload_lds16(xb + (size_t)p * KTOT + ks * 32 + kg * 8, &Xs[xbuf][base]);
      }
    };
    auto stageW = [&](int wbuf, int ks, int g) {
      const unsigned short* wb =
          Wg + (((size_t)ot * NK + ks) * 2304 + g * 768) * 8;
#pragma unroll
      for (int i = 0; i < LW; i++) {
        int base = i * THREADS + wv * 64;
        gload_lds16(wb + (size_t)(base + l) * 8, &Wl[wbuf][base]);
      }
    };
    auto computeG = [&](const bhalf8* X, const bhalf8* W, int g) {
      // all LDS reads up-front, then a pure-MFMA prio cluster (T5)
      bhalf8 BW[NREP + 2];
#pragma unroll
      for (int w10 = 0; w10 < NREP + 2; w10++) {
        int row = (pbase + w10 * 16 + l15 + g) & 255;
        BW[w10] = X[l4 * 256 + row];
      }
      bhalf8 A[3][4];
#pragma unroll
      for (int dh = 0; dh < 3; dh++)
#pragma unroll
        for (int of = 0; of < 4; of++)
          A[dh][of] = W[(dh * 4 + l4) * 64 + of * 16 + l15];
      __builtin_amdgcn_s_setprio(1);
#pragma unroll
      for (int dh = 0; dh < 3; dh++)
#pragma unroll
        for (int of = 0; of < 4; of++)
#pragma unroll
          for (int pf = 0; pf < NREP; pf++)
            acc[of][pf] = __builtin_amdgcn_mfma_f32_16x16x32_bf16(
                A[dh][of], BW[pf + dh], acc[of][pf], 0, 0, 0);
      __builtin_amdgcn_s_setprio(0);
    };

    // prologue: loads for phase (0,0) and (0,1)
    stageW(0, 0, 0); stageX(0, 0);
    stageW(1, 0, 1);

    for (int ks = 0; ks < NK - 1; ks++) {
      const bhalf8* X = Xs[ks & 1];
      // phase (ks,0): issue (ks,2) -> buf2 ; allowed in flight: (ks,1)+(ks,2)
      stageW(2, ks, 2);
      waitvm<2 * LW>();
      phase_barrier_pre();
      computeG(X, Wl[0], 0);
      phase_barrier_post();
      // phase (ks,1): issue (ks+1,0) -> buf0 + X(ks+1)
      stageW(0, ks + 1, 0); stageX((ks + 1) & 1, ks + 1);
      waitvm<2 * LW + LX>();
      phase_barrier_pre();
      computeG(X, Wl[1], 1);
      phase_barrier_post();
      // phase (ks,2): issue (ks+1,1) -> buf1
      stageW(1, ks + 1, 1);
      waitvm<2 * LW + LX>();
      phase_barrier_pre();
      computeG(X, Wl[2], 2);
      phase_barrier_post();
    }
    {  // peeled last K-step (exact tail counts)
      const bhalf8* X = Xs[(NK - 1) & 1];
      stageW(2, NK - 1, 2);
      waitvm<2 * LW>();
      phase_barrier_pre();
      computeG(X, Wl[0], 0);
      phase_barrier_post();
      waitvm<LW>();
      phase_barrier_pre();
      computeG(X, Wl[1], 1);
      phase_barrier_post();
      waitvm<0>();
      phase_barrier_pre();
      computeG(X, Wl[2], 2);
      phase_barrier_post();
    }
  } else {
    constexpr int LW = 256 / THREADS;
    constexpr int LX = 1024 / THREADS;
    static_assert(256 % THREADS == 0 && 1024 % THREADS == 0, "stage div");
    __shared__ bhalf8 Xs[3][1024];
    __shared__ bhalf8 Wl[3][256];

    auto stage1 = [&](int b, int ks) {
#pragma unroll
      for (int i = 0; i < LX; i++) {
        int base = i * THREADS + wv * 64;
        int u = base + l;
        int p = u & 255, kg = u >> 8;
        gload_lds16(xb + (size_t)p * KTOT + ks * 32 + kg * 8, &Xs[b][base]);
      }
      const unsigned short* wb = Wg + (((size_t)ot * NK + ks) * 256) * 8;
#pragma unroll
      for (int i = 0; i < LW; i++) {
        int base = i * THREADS + wv * 64;
        gload_lds16(wb + (size_t)(base + l) * 8, &Wl[b][base]);
      }
    };
    auto compute1 = [&](const bhalf8* X, const bhalf8* W) {
      bhalf8 B[NREP];
#pragma unroll
      for (int pf = 0; pf < NREP; pf++) {
        int row = (pbase + pf * 16 + l15) & 255;
        B[pf] = X[l4 * 256 + row];
      }
      bhalf8 A[4];
#pragma unroll
      for (int of = 0; of < 4; of++) A[of] = W[l4 * 64 + of * 16 + l15];
      __builtin_amdgcn_s_setprio(1);
#pragma unroll
      for (int of = 0; of < 4; of++)
#pragma unroll
        for (int pf = 0; pf < NREP; pf++)
          acc[of][pf] = __builtin_amdgcn_mfma_f32_16x16x32_bf16(
              A[of], B[pf], acc[of][pf], 0, 0, 0);
      __builtin_amdgcn_s_setprio(0);
    };

    stage1(0, 0);
    stage1(1, 1);
    int b = 0;
    for (int ks = 0; ks < NK - 2; ks++) {
      int b2 = b + 2; if (b2 >= 3) b2 -= 3;
      stage1(b2, ks + 2);
      waitvm<2 * (LW + LX)>();
      phase_barrier_pre();
      compute1(Xs[b], Wl[b]);
      phase_barrier_post();
      b = b + 1; if (b >= 3) b -= 3;
    }
    // peeled: ks = NK-2, NK-1
    waitvm<LW + LX>();
    phase_barrier_pre();
    compute1(Xs[b], Wl[b]);
    phase_barrier_post();
    b = b + 1; if (b >= 3) b -= 3;
    waitvm<0>();
    phase_barrier_pre();
    compute1(Xs[b], Wl[b]);
    phase_barrier_post();
  }

#pragma unroll
  for (int of = 0; of < 4; of++) {
    int og = ot * 64 + of * 16 + l4 * 4;
    int tensor = og >> 9, ol = og & 511;
#pragma unroll
    for (int pf = 0; pf < NREP; pf++) {
      int p = pbase + pf * 16 + l15;
      int po = p;
      if (VALID) {
        int h = p >> 4, w = p & 15;
        if (h >= 14 || w >= 14) continue;
        po = (h + 1) * 16 + (w + 1);
      }
      unsigned short* dp = Out + (((size_t)tensor * 32 + n) * 256 + po) * 512 + ol;
      float vv[4];
#pragma unroll
      for (int r2 = 0; r2 < 4; r2++) vv[r2] = acc[of][pf][r2];
      if (BIAS) {
#pragma unroll
        for (int r2 = 0; r2 < 4; r2++) vv[r2] += bias[(size_t)n * 512 + ol + r2];
      }
      if (ADD) {
        ushort4 old = *(const ushort4*)dp;
        vv[0] += b2f(old.x); vv[1] += b2f(old.y); vv[2] += b2f(old.z); vv[3] += b2f(old.w);
      }
      if (RELU) {
#pragma unroll
        for (int r2 = 0; r2 < 4; r2++) vv[r2] = fmaxf(vv[r2], 0.f);
      }
      ushort4 st = { f2b(vv[0]), f2b(vv[1]), f2b(vv[2]), f2b(vv[3]) };
      *(ushort4*)dp = st;
    }
  }
}

// ---- att[qn][pp][kn] = (1/sqrt(512)) * sum_c q[qn][pp][c]*k[kn][pp][c] ----
__global__ __launch_bounds__(256) void att2_kernel(
    const unsigned short* __restrict__ q, const unsigned short* __restrict__ k,
    float* __restrict__ att) {
  int kn = blockIdx.x, qn = blockIdx.y;
  int t = threadIdx.x, wv = t >> 6, l = t & 63;
  const unsigned short* qb = q + (size_t)qn * ACT_N;
  const unsigned short* kb = k + (size_t)kn * ACT_N;
  for (int i = wv; i < 196; i += 4) {
    int pp = (i / 14 + 1) * 16 + (i % 14) + 1;
    bhalf8 qv = *(const bhalf8*)(qb + pp * 512 + l * 8);
    bhalf8 kv = *(const bhalf8*)(kb + pp * 512 + l * 8);
    float s = 0.f;
#pragma unroll
    for (int j = 0; j < 8; j++)
      s += b2f((unsigned short)qv[j]) * b2f((unsigned short)kv[j]);
#pragma unroll
    for (int off = 32; off >= 1; off >>= 1) s += __shfl_xor(s, off);
    if (l == 0) att[((size_t)qn * 256 + pp) * 32 + kn] = s * 0.044194173824159216f;
  }
}

// ---- softmax over kn (32 contiguous f32 per (qn,pp)) ----
__global__ void softmax2_kernel(float* __restrict__ att) {
  int qn = blockIdx.x, t = threadIdx.x;
  if (t >= 196) return;
  int pp = (t / 14 + 1) * 16 + (t % 14) + 1;
  float* a = att + ((size_t)qn * 256 + pp) * 32;
  float v[32]; float m = -3.4e38f;
#pragma unroll
  for (int i = 0; i < 32; i++) { v[i] = a[i]; m = fmaxf(m, v[i]); }
  float s = 0.f;
#pragma unroll
  for (int i = 0; i < 32; i++) { v[i] = __expf(v[i] - m); s += v[i]; }
  float inv = 1.f / s;
#pragma unroll
  for (int i = 0; i < 32; i++) a[i] = v[i] * inv;
}

// ---- vf[qn][p][c] = sum_kn att[qn][p][kn]*v[kn][p][c]; border rows -> 0 ----
__global__ __launch_bounds__(256) void vf2_kernel(
    const float* __restrict__ att, const unsigned short* __restrict__ v,
    unsigned short* __restrict__ o) {
  int p = blockIdx.x, t = threadIdx.x;
  int h = p >> 4, w = p & 15;
  if (h < 1 || h > 14 || w < 1 || w > 14) {
    for (int qn = 0; qn < 32; qn++)
      *(unsigned int*)(o + ((size_t)qn * 256 + p) * 512 + t * 2) = 0u;
    return;
  }
  __shared__ float attS[1024];
  __shared__ unsigned short vS[32 * 512];
#pragma unroll
  for (int i = 0; i < 4; i++) {
    int idx = t + i * 256;
    int qn = idx >> 5, kn = idx & 31;
    attS[idx] = att[((size_t)qn * 256 + p) * 32 + kn];
  }
#pragma unroll
  for (int i = 0; i < 8; i++) {
    int u = t + i * 256;
    int kn = u >> 6, cu = (u & 63) * 8;
    *(bhalf8*)&vS[kn * 512 + cu] = *(const bhalf8*)(v + ((size_t)kn * 256 + p) * 512 + cu);
  }
  __syncthreads();
  int c2 = t * 2;
  for (int qn = 0; qn < 32; qn++) {
    float s0 = 0.f, s1 = 0.f;
#pragma unroll
    for (int kn = 0; kn < 32; kn++) {
      float a = attS[qn * 32 + kn];
      unsigned int vv = *(const unsigned int*)&vS[kn * 512 + c2];
      s0 += a * b2f((unsigned short)vv);
      s1 += a * b2f((unsigned short)(vv >> 16));
    }
    unsigned int pkd = (unsigned int)f2b(s0) | ((unsigned int)f2b(s1) << 16);
    *(unsigned int*)(o + ((size_t)qn * 256 + p) * 512 + c2) = pkd;
  }
}

// ---- GroupNorm stats over interior (196 x 512) per n ----
__global__ __launch_bounds__(256) void gnstats2_kernel(
    const unsigned short* __restrict__ x, float* __restrict__ stats) {
  int n = blockIdx.x, t = threadIdx.x;
  const unsigned short* xb = x + (size_t)n * ACT_N;
  float s = 0.f, ss = 0.f;
  for (int i = 0; i < 196; i++) {
    int pp = (i / 14 + 1) * 16 + (i % 14) + 1;
    unsigned int vv = *(const unsigned int*)(xb + pp * 512 + t * 2);
    float a = b2f((unsigned short)vv), b = b2f((unsigned short)(vv >> 16));
    s += a + b; ss += a * a + b * b;
  }
#pragma unroll
  for (int off = 32; off >= 1; off >>= 1) { s += __shfl_xor(s, off); ss += __shfl_xor(ss, off); }
  __shared__ float sm[8];
  int wv = t >> 6, ln = t & 63;
  if (ln == 0) { sm[wv] = s; sm[4 + wv] = ss; }
  __syncthreads();
  if (t == 0) {
    stats[n * 2]     = sm[0] + sm[1] + sm[2] + sm[3];
    stats[n * 2 + 1] = sm[4] + sm[5] + sm[6] + sm[7];
  }
}

// ---- GroupNorm apply + affine + relu (interior only) ----
__global__ __launch_bounds__(256) void gnapply2_kernel(
    unsigned short* __restrict__ x, const float* __restrict__ stats,
    const float* __restrict__ gamma, const float* __restrict__ beta) {
  int n = blockIdx.y, t = threadIdx.x;
  int c2 = t * 2;
  unsigned short* xb = x + (size_t)n * ACT_N;
  const float M = 512.f * 196.f;
  float mu = stats[n * 2] / M;
  float var = stats[n * 2 + 1] / M - mu * mu;
  float inv = rsqrtf(var + 1e-5f);
  float g0 = gamma[c2], g1 = gamma[c2 + 1];
  float be0 = beta[c2], be1 = beta[c2 + 1];
  for (int j = 0; j < 28; j++) {
    int i = blockIdx.x * 28 + j;
    int pp = (i / 14 + 1) * 16 + (i % 14) + 1;
    unsigned int vv = *(unsigned int*)(xb + pp * 512 + c2);
    float a = (b2f((unsigned short)vv) - mu) * inv * g0 + be0;
    float b = (b2f((unsigned short)(vv >> 16)) - mu) * inv * g1 + be1;
    a = fmaxf(a, 0.f); b = fmaxf(b, 0.f);
    *(unsigned int*)(xb + pp * 512 + c2) =
        (unsigned int)f2b(a) | ((unsigned int)f2b(b) << 16);
  }
}

// ---- final: mean over interior 196 -> out[n][1024+c] (f32) ----
__global__ void fmean2_kernel(const unsigned short* __restrict__ x, float* __restrict__ out) {
  int n = blockIdx.x, t = threadIdx.x;
  const unsigned short* xb = x + (size_t)n * ACT_N;
  float s0 = 0.f, s1 = 0.f;
  for (int i = 0; i < 196; i++) {
    int pp = (i / 14 + 1) * 16 + (i % 14) + 1;
    unsigned int vv = *(const unsigned int*)(xb + pp * 512 + t * 2);
    s0 += b2f((unsigned short)vv);
    s1 += b2f((unsigned short)(vv >> 16));
  }
  out[(size_t)n * 1536 + 1024 + t * 2]     = s0 * (1.f / 196.f);
  out[(size_t)n * 1536 + 1024 + t * 2 + 1] = s1 * (1.f / 196.f);
}

extern "C" void kernel_launch(void* const* d_in, const int* in_sizes, int n_in,
                              void* d_out, int out_size, void* d_ws, size_t ws_size,
                              hipStream_t stream) {
  const float* x     = (const float*)d_in[0];
  const float* feat  = (const float*)d_in[1];
  const int*   rois  = (const int*)d_in[2];
  const float* w1    = (const float*)d_in[3];
  const float* w2    = (const float*)d_in[4];
  const float* wq    = (const float*)d_in[5];
  const float* wk    = (const float*)d_in[6];
  const float* wv    = (const float*)d_in[7];
  const float* wm    = (const float*)d_in[8];
  const float* gamma = (const float*)d_in[9];
  const float* beta  = (const float*)d_in[10];
  float* out = (float*)d_out;

  // ---- workspace layout ----
  float* wsf   = (float*)d_ws;
  float* xp    = wsf;                // 32768
  float* bias1 = xp + 32768;         // 16384
  float* stats = bias1 + 16384;      // 64
  float* att   = stats + 64;         // 262144  ([qn][pp][kn] f32)
  unsigned short* ub    = (unsigned short*)(att + 262144);
  unsigned short* featT = ub;                    // 8*256*1024   = 2097152
  unsigned short* W1g   = featT + 2097152;       // 512*1024     = 524288
  unsigned short* Wg2   = W1g + 524288;          // 13*W3SZ      = 30670848
  unsigned short* bufq  = Wg2 + 30670848;        // 4194304 each, q/k/v contiguous
  unsigned short* bufk  = bufq + 4194304;
  unsigned short* bufv  = bufk + 4194304;
  unsigned short* bufx  = bufv + 4194304;

  // bufx border rows must be zero (only interior ever written by convs)
  hipMemsetAsync(bufx, 0, (size_t)4194304 * 2, stream);

  pool_max_kernel<<<8192, 256, 0, stream>>>(x, xp, out);
  bias1_kernel<<<4096, 256, 0, stream>>>(w1, xp, bias1);
  wprep3_kernel<<<dim3(16, 8, 13), 256, 0, stream>>>(w2, wq, wk, wv, wm, Wg2);
  w1prep_kernel<<<dim3(32, 8), 256, 0, stream>>>(w1, W1g);
  ftprep_kernel<<<dim3(4, 16, 8), 256, 0, stream>>>(feat, featT);

  // conv1: 1x1, K=1024, +bias1, relu, full 16x16 output -> bufq
  conv_mfma_kernel<1, 1024, 4, 4, 1, true, false, true, false>
      <<<dim3(8, 32), 256, 0, stream>>>(featT, rois, W1g, bias1, bufq);
  // conv2: valid 3x3 -> padded interior of bufx, relu (4-wave shape)
  conv_mfma_kernel<9, 512, 4, 4, 1, true, false, false, true>
      <<<dim3(8, 32), 256, 0, stream>>>(bufq, nullptr, Wg2, nullptr, bufx);

  for (int d = 0; d < 3; d++) {
    // q,k,v batched: O=1536 over contiguous blocked tensors / output buffers
    conv_mfma_kernel<9, 512, 4, 4, 1, false, false, false, true>
        <<<dim3(24, 32), 256, 0, stream>>>(bufx, nullptr,
            Wg2 + (size_t)(1 + 4 * d) * W3SZ, nullptr, bufq);
    att2_kernel<<<dim3(32, 32), 256, 0, stream>>>(bufq, bufk, att);
    softmax2_kernel<<<32, 256, 0, stream>>>(att);
    vf2_kernel<<<256, 256, 0, stream>>>(att, bufv, bufq);
    gnstats2_kernel<<<32, 256, 0, stream>>>(bufq, stats);
    gnapply2_kernel<<<dim3(7, 32), 256, 0, stream>>>(bufq, stats,
        gamma + d * 512, beta + d * 512);
    // wm conv + residual add into bufx (4-wave shape)
    conv_mfma_kernel<9, 512, 4, 4, 1, false, true, false, true>
        <<<dim3(8, 32), 256, 0, stream>>>(bufq, nullptr,
            Wg2 + (size_t)(4 + 4 * d) * W3SZ, nullptr, bufx);
  }

  fmean2_kernel<<<32, 256, 0, stream>>>(bufx, out);
}

// Round 9
// 788.400 us; speedup vs baseline: 1.2093x; 1.1253x over previous
//
#include <hip/hip_runtime.h>

// ---------------------------------------------------------------------------
// ACARHead forward. bf16-MFMA convs (depth-2 counted-vmcnt pipeline + setprio)
// + fully-fused MFMA attention (QK^T -> in-register softmax -> PV) with
// GroupNorm partials computed in-flight.
// Activation layout: bf16 [n][p=256][c]; 14x14 payload at rows/cols 1..14.
// ---------------------------------------------------------------------------

typedef __attribute__((ext_vector_type(8))) short bhalf8;
typedef __attribute__((ext_vector_type(4))) float floatx4;

#define ACT_N 131072   // 256*512 bf16 elements per sample
#define W3SZ  2359296  // 512*512*9 (also = blocked per-tensor short count)

__device__ inline float b2f(unsigned short u) {
  union { unsigned int i; float f; } x; x.i = ((unsigned int)u) << 16; return x.f;
}
__device__ inline unsigned short f2b(float f) {
  union { float f; unsigned int i; } x; x.f = f;
  return (unsigned short)((x.i + 0x7FFFu + ((x.i >> 16) & 1u)) >> 16);
}
__device__ inline void gload_lds16(const unsigned short* g, bhalf8* l) {
  __builtin_amdgcn_global_load_lds(
      (const __attribute__((address_space(1))) unsigned int*)(const void*)g,
      (__attribute__((address_space(3))) unsigned int*)(void*)l, 16, 0, 0);
}
template <int N> __device__ inline void waitvm() {
  asm volatile("s_waitcnt vmcnt(%0)" :: "i"(N) : "memory");
}
__device__ inline void phase_barrier_pre() {
  __builtin_amdgcn_sched_barrier(0);
  __builtin_amdgcn_s_barrier();
  __builtin_amdgcn_sched_barrier(0);
}
__device__ inline void phase_barrier_post() {
  __builtin_amdgcn_sched_barrier(0);
  __builtin_amdgcn_s_barrier();
  __builtin_amdgcn_sched_barrier(0);
}

// ---- AdaptiveMaxPool3d(1): max over 196, write xp (f32) and out[:,0:1024] ----
__global__ void pool_max_kernel(const float* __restrict__ x, float* __restrict__ xp,
                                float* __restrict__ out) {
  int tid = threadIdx.x;
  int wid = blockIdx.x * 4 + (tid >> 6);   // n*1024 + c
  int lane = tid & 63;
  int n = wid >> 10, c = wid & 1023;
  const float* p = x + (size_t)wid * 196;
  float v = -3.4e38f;
  v = fmaxf(v, p[lane]);
  v = fmaxf(v, p[lane + 64]);
  v = fmaxf(v, p[lane + 128]);
  if (lane < 4) v = fmaxf(v, p[lane + 192]);
#pragma unroll
  for (int off = 32; off >= 1; off >>= 1) v = fmaxf(v, __shfl_xor(v, off));
  if (lane == 0) { xp[wid] = v; out[(size_t)n * 1536 + c] = v; }
}

// ---- bias1[n][o] = sum_{c<1024} w1[o][1024+c] * xp[n][c]  (f32) ----
__global__ void bias1_kernel(const float* __restrict__ w1, const float* __restrict__ xp,
                             float* __restrict__ bias1) {
  int tid = threadIdx.x;
  int wid = blockIdx.x * 4 + (tid >> 6);   // n*512 + o
  int lane = tid & 63;
  int n = wid >> 9, o = wid & 511;
  const float* wr = w1 + (size_t)o * 2048 + 1024;
  const float* xr = xp + (size_t)n * 1024;
  float s = 0.f;
#pragma unroll
  for (int r = 0; r < 16; r++) { int c = lane + r * 64; s += wr[c] * xr[c]; }
#pragma unroll
  for (int off = 32; off >= 1; off >>= 1) s += __shfl_xor(s, off);
  if (lane == 0) bias1[wid] = s;
}

// ---- 3x3 weight prep -> tap-grouped blocked layout ----
__global__ __launch_bounds__(256) void wprep3_kernel(
    const float* __restrict__ w2, const float* __restrict__ wq,
    const float* __restrict__ wk, const float* __restrict__ wv,
    const float* __restrict__ wm, unsigned short* __restrict__ Wg2) {
  int ks = blockIdx.x, ot = blockIdx.y, tid = blockIdx.z;
  int t = threadIdx.x;
  const float* src;
  if (tid == 0) src = w2;
  else {
    int d = (tid - 1) >> 2, r = (tid - 1) & 3;
    src = (r == 0 ? wq : r == 1 ? wk : r == 2 ? wv : wm) + (size_t)d * W3SZ;
  }
  __shared__ unsigned short S[64 * 288];
  const float* sb = src + (size_t)ot * 64 * 4608 + (size_t)ks * 288;
  for (int j = 0; j < 72; j++) {
    int flat = j * 256 + t;          // < 18432
    int o = flat / 288, ci = flat % 288;
    S[flat] = f2b(sb[(size_t)o * 4608 + ci]);
  }
  __syncthreads();
  unsigned short* dst = Wg2 + (((size_t)(tid * 8 + ot) * 16 + ks) * 2304) * 8;
#pragma unroll
  for (int s = 0; s < 9; s++) {
    int u = t + s * 256;
    int g = u / 768, rem = u % 768;
    int rl = rem >> 6, o = rem & 63;
    int dh = rl >> 2, kg = rl & 3;
    int t9src = dh * 3 + g;
    bhalf8 v;
#pragma unroll
    for (int j = 0; j < 8; j++) v[j] = (short)S[o * 288 + (kg * 8 + j) * 9 + t9src];
    *(bhalf8*)(dst + (size_t)u * 8) = v;
  }
}

// ---- conv1 weight prep -> blocked: W1g[ot(8)][ks(32)][slot(256)][8] ----
__global__ void w1prep_kernel(const float* __restrict__ w1, unsigned short* __restrict__ W1g) {
  int ks = blockIdx.x, ot = blockIdx.y, t = threadIdx.x;
  int kg = t >> 6, o = t & 63;
  const float* s = w1 + (size_t)(ot * 64 + o) * 2048 + ks * 32 + kg * 8;
  bhalf8 v;
#pragma unroll
  for (int j = 0; j < 8; j++) v[j] = (short)f2b(s[j]);
  *(bhalf8*)(W1g + (((size_t)ot * 32 + ks) * 256 + t) * 8) = v;
}

// ---- feat transpose: feat[img][c][p] f32 -> featT[img][p][c] bf16 ----
__global__ __launch_bounds__(256) void ftprep_kernel(
    const float* __restrict__ feat, unsigned short* __restrict__ featT) {
  int img = blockIdx.z, c0 = blockIdx.y * 64, p0 = blockIdx.x * 64;
  int t = threadIdx.x;
  int a = t >> 6, b = t & 63;
  __shared__ float S[64][65];
#pragma unroll
  for (int j = 0; j < 16; j++) {
    int r = a * 16 + j;
    S[r][b] = feat[((size_t)img * 1024 + c0 + r) * 256 + p0 + b];
  }
  __syncthreads();
#pragma unroll
  for (int j = 0; j < 16; j++) {
    int pl = a * 16 + j;
    featT[((size_t)img * 256 + p0 + pl) * 1024 + c0 + b] = f2b(S[b][pl]);
  }
}

// ---------------------------------------------------------------------------
// Unified MFMA conv, depth-2 counted-vmcnt pipeline + setprio MFMA clusters.
// ---------------------------------------------------------------------------
template <int TAPS, int KTOT, int WAVES, int NREP, int PSPLIT,
          bool RELU, bool ADD, bool BIAS, bool VALID>
__global__ __launch_bounds__(WAVES * 64) void conv_mfma_kernel(
    const unsigned short* __restrict__ Xg, const int* __restrict__ rois,
    const unsigned short* __restrict__ Wg, const float* __restrict__ bias,
    unsigned short* __restrict__ Out) {
  constexpr int THREADS = WAVES * 64;
  constexpr int NK = KTOT / 32;
  static_assert(PSPLIT * WAVES * NREP * 16 == 256, "p coverage");

  int n = blockIdx.y;
  int ot = blockIdx.x / PSPLIT;
  int pq = blockIdx.x % PSPLIT;
  int t = threadIdx.x;
  int wv = t >> 6, l = t & 63, l15 = l & 15, l4 = l >> 4;
  int pbase = (pq * WAVES + wv) * (NREP * 16);
  const unsigned short* xb =
      Xg + (rois ? (size_t)rois[n * 5] * 256 * KTOT : (size_t)n * 256 * KTOT);
  floatx4 acc[4][NREP] = {};

  if constexpr (TAPS == 9) {
    constexpr int LW = 768 / THREADS;
    constexpr int LX = 1024 / THREADS;
    static_assert(768 % THREADS == 0 && 1024 % THREADS == 0, "stage div");
    __shared__ bhalf8 Xs[2][1024];
    __shared__ bhalf8 Wl[3][768];

    auto stageX = [&](int xbuf, int ks) {
#pragma unroll
      for (int i = 0; i < LX; i++) {
        int base = i * THREADS + wv * 64;
        int u = base + l;
        int p = u & 255, kg = u >> 8;
        gload_lds16(xb + (size_t)p * KTOT + ks * 32 + kg * 8, &Xs[xbuf][base]);
      }
    };
    auto stageW = [&](int wbuf, int ks, int g) {
      const unsigned short* wb =
          Wg + (((size_t)ot * NK + ks) * 2304 + g * 768) * 8;
#pragma unroll
      for (int i = 0; i < LW; i++) {
        int base = i * THREADS + wv * 64;
        gload_lds16(wb + (size_t)(base + l) * 8, &Wl[wbuf][base]);
      }
    };
    auto computeG = [&](const bhalf8* X, const bhalf8* W, int g) {
      bhalf8 BW[NREP + 2];
#pragma unroll
      for (int w10 = 0; w10 < NREP + 2; w10++) {
        int row = (pbase + w10 * 16 + l15 + g) & 255;
        BW[w10] = X[l4 * 256 + row];
      }
      bhalf8 A[3][4];
#pragma unroll
      for (int dh = 0; dh < 3; dh++)
#pragma unroll
        for (int of = 0; of < 4; of++)
          A[dh][of] = W[(dh * 4 + l4) * 64 + of * 16 + l15];
      __builtin_amdgcn_s_setprio(1);
#pragma unroll
      for (int dh = 0; dh < 3; dh++)
#pragma unroll
        for (int of = 0; of < 4; of++)
#pragma unroll
          for (int pf = 0; pf < NREP; pf++)
            acc[of][pf] = __builtin_amdgcn_mfma_f32_16x16x32_bf16(
                A[dh][of], BW[pf + dh], acc[of][pf], 0, 0, 0);
      __builtin_amdgcn_s_setprio(0);
    };

    stageW(0, 0, 0); stageX(0, 0);
    stageW(1, 0, 1);

    for (int ks = 0; ks < NK - 1; ks++) {
      const bhalf8* X = Xs[ks & 1];
      stageW(2, ks, 2);
      waitvm<2 * LW>();
      phase_barrier_pre();
      computeG(X, Wl[0], 0);
      phase_barrier_post();
      stageW(0, ks + 1, 0); stageX((ks + 1) & 1, ks + 1);
      waitvm<2 * LW + LX>();
      phase_barrier_pre();
      computeG(X, Wl[1], 1);
      phase_barrier_post();
      stageW(1, ks + 1, 1);
      waitvm<2 * LW + LX>();
      phase_barrier_pre();
      computeG(X, Wl[2], 2);
      phase_barrier_post();
    }
    {
      const bhalf8* X = Xs[(NK - 1) & 1];
      stageW(2, NK - 1, 2);
      waitvm<2 * LW>();
      phase_barrier_pre();
      computeG(X, Wl[0], 0);
      phase_barrier_post();
      waitvm<LW>();
      phase_barrier_pre();
      computeG(X, Wl[1], 1);
      phase_barrier_post();
      waitvm<0>();
      phase_barrier_pre();
      computeG(X, Wl[2], 2);
      phase_barrier_post();
    }
  } else {
    constexpr int LW = 256 / THREADS;
    constexpr int LX = 1024 / THREADS;
    static_assert(256 % THREADS == 0 && 1024 % THREADS == 0, "stage div");
    __shared__ bhalf8 Xs[3][1024];
    __shared__ bhalf8 Wl[3][256];

    auto stage1 = [&](int b, int ks) {
#pragma unroll
      for (int i = 0; i < LX; i++) {
        int base = i * THREADS + wv * 64;
        int u = base + l;
        int p = u & 255, kg = u >> 8;
        gload_lds16(xb + (size_t)p * KTOT + ks * 32 + kg * 8, &Xs[b][base]);
      }
      const unsigned short* wb = Wg + (((size_t)ot * NK + ks) * 256) * 8;
#pragma unroll
      for (int i = 0; i < LW; i++) {
        int base = i * THREADS + wv * 64;
        gload_lds16(wb + (size_t)(base + l) * 8, &Wl[b][base]);
      }
    };
    auto compute1 = [&](const bhalf8* X, const bhalf8* W) {
      bhalf8 B[NREP];
#pragma unroll
      for (int pf = 0; pf < NREP; pf++) {
        int row = (pbase + pf * 16 + l15) & 255;
        B[pf] = X[l4 * 256 + row];
      }
      bhalf8 A[4];
#pragma unroll
      for (int of = 0; of < 4; of++) A[of] = W[l4 * 64 + of * 16 + l15];
      __builtin_amdgcn_s_setprio(1);
#pragma unroll
      for (int of = 0; of < 4; of++)
#pragma unroll
        for (int pf = 0; pf < NREP; pf++)
          acc[of][pf] = __builtin_amdgcn_mfma_f32_16x16x32_bf16(
              A[of], B[pf], acc[of][pf], 0, 0, 0);
      __builtin_amdgcn_s_setprio(0);
    };

    stage1(0, 0);
    stage1(1, 1);
    int b = 0;
    for (int ks = 0; ks < NK - 2; ks++) {
      int b2 = b + 2; if (b2 >= 3) b2 -= 3;
      stage1(b2, ks + 2);
      waitvm<2 * (LW + LX)>();
      phase_barrier_pre();
      compute1(Xs[b], Wl[b]);
      phase_barrier_post();
      b = b + 1; if (b >= 3) b -= 3;
    }
    waitvm<LW + LX>();
    phase_barrier_pre();
    compute1(Xs[b], Wl[b]);
    phase_barrier_post();
    b = b + 1; if (b >= 3) b -= 3;
    waitvm<0>();
    phase_barrier_pre();
    compute1(Xs[b], Wl[b]);
    phase_barrier_post();
  }

#pragma unroll
  for (int of = 0; of < 4; of++) {
    int og = ot * 64 + of * 16 + l4 * 4;
    int tensor = og >> 9, ol = og & 511;
#pragma unroll
    for (int pf = 0; pf < NREP; pf++) {
      int p = pbase + pf * 16 + l15;
      int po = p;
      if (VALID) {
        int h = p >> 4, w = p & 15;
        if (h >= 14 || w >= 14) continue;
        po = (h + 1) * 16 + (w + 1);
      }
      unsigned short* dp = Out + (((size_t)tensor * 32 + n) * 256 + po) * 512 + ol;
      float vv[4];
#pragma unroll
      for (int r2 = 0; r2 < 4; r2++) vv[r2] = acc[of][pf][r2];
      if (BIAS) {
#pragma unroll
        for (int r2 = 0; r2 < 4; r2++) vv[r2] += bias[(size_t)n * 512 + ol + r2];
      }
      if (ADD) {
        ushort4 old = *(const ushort4*)dp;
        vv[0] += b2f(old.x); vv[1] += b2f(old.y); vv[2] += b2f(old.z); vv[3] += b2f(old.w);
      }
      if (RELU) {
#pragma unroll
        for (int r2 = 0; r2 < 4; r2++) vv[r2] = fmaxf(vv[r2], 0.f);
      }
      ushort4 st = { f2b(vv[0]), f2b(vv[1]), f2b(vv[2]), f2b(vv[3]) };
      *(ushort4*)dp = st;
    }
  }
}

// ---- V transpose: bufv[kn][pp][c] -> vt[ppc][c][kn]  (interior pp only) ----
__global__ __launch_bounds__(256) void vtrans_kernel(
    const unsigned short* __restrict__ v, unsigned short* __restrict__ vt) {
  int ppc = blockIdx.x;                       // 0..195
  int pp = (ppc / 14 + 1) * 16 + ppc % 14 + 1;
  int t = threadIdx.x;
  __shared__ unsigned short S[32 * 512];
#pragma unroll
  for (int i = 0; i < 8; i++) {
    int u = i * 256 + t;
    int kn = u >> 6, c8 = (u & 63) * 8;
    *(bhalf8*)&S[kn * 512 + c8] = *(const bhalf8*)(v + ((size_t)kn * 256 + pp) * 512 + c8);
  }
  __syncthreads();
#pragma unroll
  for (int half = 0; half < 2; half++) {
    int c = half * 256 + t;
    unsigned int col[16];
#pragma unroll
    for (int j = 0; j < 16; j++)
      col[j] = (unsigned int)S[(2 * j) * 512 + c] |
               ((unsigned int)S[(2 * j + 1) * 512 + c] << 16);
    unsigned short* dst = vt + ((size_t)ppc * 512 + c) * 32;
#pragma unroll
    for (int j = 0; j < 4; j++) {
      uint4 P = { col[j * 4], col[j * 4 + 1], col[j * 4 + 2], col[j * 4 + 3] };
      *(uint4*)(dst + j * 8) = P;
    }
  }
}

// ---------------------------------------------------------------------------
// Fused attention per pixel: QK^T (MFMA) -> in-register softmax -> PV (MFMA,
// C^T form via pre-transposed V) -> store vf + GroupNorm partials.
// 1 wave per block; grid 256 (border blocks just zero their slice).
// ---------------------------------------------------------------------------
__global__ __launch_bounds__(64) void attfused_kernel(
    const unsigned short* __restrict__ q, const unsigned short* __restrict__ k,
    const unsigned short* __restrict__ vt, unsigned short* __restrict__ out,
    float* __restrict__ gnpart) {
  int pp = blockIdx.x;
  int h = pp >> 4, w = pp & 15;
  int l = threadIdx.x, l15 = l & 15, l4 = l >> 4;
  if (h < 1 || h > 14 || w < 1 || w > 14) {
    uint4 z = {0u, 0u, 0u, 0u};
#pragma unroll
    for (int qn = 0; qn < 32; qn++)
      *(uint4*)(out + ((size_t)qn * 256 + pp) * 512 + l * 8) = z;
    return;
  }
  int ppc = (h - 1) * 14 + (w - 1);

  // ---- QK^T: C[kn32][qn32], K=512 ----
  floatx4 sc[2][2] = {};
#pragma unroll
  for (int kb = 0; kb < 16; kb++) {
    bhalf8 A[2], B[2];
#pragma unroll
    for (int of = 0; of < 2; of++)
      A[of] = *(const bhalf8*)(k + ((size_t)(of * 16 + l15) * 256 + pp) * 512 + kb * 32 + l4 * 8);
#pragma unroll
    for (int pf = 0; pf < 2; pf++)
      B[pf] = *(const bhalf8*)(q + ((size_t)(pf * 16 + l15) * 256 + pp) * 512 + kb * 32 + l4 * 8);
#pragma unroll
    for (int of = 0; of < 2; of++)
#pragma unroll
      for (int pf = 0; pf < 2; pf++)
        sc[of][pf] = __builtin_amdgcn_mfma_f32_16x16x32_bf16(A[of], B[pf], sc[of][pf], 0, 0, 0);
  }

  // ---- softmax over kn (rows), per qn column; P -> LDS bf16 normalized ----
  __shared__ unsigned short p_lds[32 * 32];
  const float scale = 0.044194173824159216f;
#pragma unroll
  for (int pf = 0; pf < 2; pf++) {
    float v8[8];
    float m = -3.4e38f;
#pragma unroll
    for (int of = 0; of < 2; of++)
#pragma unroll
      for (int r = 0; r < 4; r++) {
        float x = sc[of][pf][r] * scale;
        v8[of * 4 + r] = x;
        m = fmaxf(m, x);
      }
    m = fmaxf(m, __shfl_xor(m, 16));
    m = fmaxf(m, __shfl_xor(m, 32));
    float s = 0.f;
#pragma unroll
    for (int i = 0; i < 8; i++) { v8[i] = __expf(v8[i] - m); s += v8[i]; }
    s += __shfl_xor(s, 16);
    s += __shfl_xor(s, 32);
    float inv = 1.f / s;
#pragma unroll
    for (int of = 0; of < 2; of++) {
      ushort4 pk = { f2b(v8[of * 4 + 0] * inv), f2b(v8[of * 4 + 1] * inv),
                     f2b(v8[of * 4 + 2] * inv), f2b(v8[of * 4 + 3] * inv) };
      *(ushort4*)&p_lds[(pf * 16 + l15) * 32 + of * 16 + l4 * 4] = pk;
    }
  }

  // ---- PV as C^T: C[c512][qn32] = VT[c][kn] @ P[qn][kn]^T, K=32 ----
  bhalf8 PB[2];
#pragma unroll
  for (int qf = 0; qf < 2; qf++)
    PB[qf] = *(const bhalf8*)&p_lds[(qf * 16 + l15) * 32 + l4 * 8];
  float gs[2] = {0.f, 0.f}, gss[2] = {0.f, 0.f};
  const unsigned short* vtb = vt + (size_t)ppc * 512 * 32;
#pragma unroll
  for (int chunk = 0; chunk < 4; chunk++) {
    bhalf8 VA[8];
#pragma unroll
    for (int co = 0; co < 8; co++)
      VA[co] = *(const bhalf8*)(vtb + (size_t)(chunk * 128 + co * 16 + l15) * 32 + l4 * 8);
#pragma unroll
    for (int co = 0; co < 8; co++)
#pragma unroll
      for (int qf = 0; qf < 2; qf++) {
        floatx4 pa = __builtin_amdgcn_mfma_f32_16x16x32_bf16(
            VA[co], PB[qf], (floatx4){0.f, 0.f, 0.f, 0.f}, 0, 0, 0);
        float x0 = pa[0], x1 = pa[1], x2 = pa[2], x3 = pa[3];
        gs[qf] += x0 + x1 + x2 + x3;
        gss[qf] += x0 * x0 + x1 * x1 + x2 * x2 + x3 * x3;
        ushort4 st = { f2b(x0), f2b(x1), f2b(x2), f2b(x3) };
        int qn = qf * 16 + l15;
        int c = chunk * 128 + co * 16 + l4 * 4;
        *(ushort4*)(out + ((size_t)qn * 256 + pp) * 512 + c) = st;
      }
  }
  // reduce partials over l4 (c quarters) -> per-qn sums
#pragma unroll
  for (int qf = 0; qf < 2; qf++) {
    gs[qf] += __shfl_xor(gs[qf], 16);  gs[qf] += __shfl_xor(gs[qf], 32);
    gss[qf] += __shfl_xor(gss[qf], 16); gss[qf] += __shfl_xor(gss[qf], 32);
  }
  if (l4 == 0) {
#pragma unroll
    for (int qf = 0; qf < 2; qf++) {
      int qn = qf * 16 + l15;
      gnpart[((size_t)ppc * 32 + qn) * 2]     = gs[qf];
      gnpart[((size_t)ppc * 32 + qn) * 2 + 1] = gss[qf];
    }
  }
}

// ---- GroupNorm: reduce partials + apply affine + relu (interior only) ----
__global__ __launch_bounds__(256) void gnapply3_kernel(
    unsigned short* __restrict__ x, const float* __restrict__ gnpart,
    const float* __restrict__ gamma, const float* __restrict__ beta) {
  int n = blockIdx.y, half = blockIdx.x, t = threadIdx.x;
  float s = 0.f, ss = 0.f;
  if (t < 196) {
    s  = gnpart[((size_t)t * 32 + n) * 2];
    ss = gnpart[((size_t)t * 32 + n) * 2 + 1];
  }
#pragma unroll
  for (int off = 32; off >= 1; off >>= 1) { s += __shfl_xor(s, off); ss += __shfl_xor(ss, off); }
  __shared__ float sm[8];
  int wv = t >> 6, ln = t & 63;
  if (ln == 0) { sm[wv] = s; sm[4 + wv] = ss; }
  __syncthreads();
  float S = sm[0] + sm[1] + sm[2] + sm[3];
  float SS = sm[4] + sm[5] + sm[6] + sm[7];
  const float M = 512.f * 196.f;
  float mu = S / M;
  float var = SS / M - mu * mu;
  float inv = rsqrtf(var + 1e-5f);
  int c2 = t * 2;
  unsigned short* xb = x + (size_t)n * ACT_N;
  float g0 = gamma[c2], g1 = gamma[c2 + 1];
  float be0 = beta[c2], be1 = beta[c2 + 1];
  for (int i = 0; i < 98; i++) {
    int ppc = half * 98 + i;
    int pp = (ppc / 14 + 1) * 16 + ppc % 14 + 1;
    unsigned int vv = *(unsigned int*)(xb + pp * 512 + c2);
    float a = (b2f((unsigned short)vv) - mu) * inv * g0 + be0;
    float b = (b2f((unsigned short)(vv >> 16)) - mu) * inv * g1 + be1;
    a = fmaxf(a, 0.f); b = fmaxf(b, 0.f);
    *(unsigned int*)(xb + pp * 512 + c2) =
        (unsigned int)f2b(a) | ((unsigned int)f2b(b) << 16);
  }
}

// ---- final: mean over interior 196 -> out[n][1024+c] (f32) ----
__global__ void fmean2_kernel(const unsigned short* __restrict__ x, float* __restrict__ out) {
  int n = blockIdx.x, t = threadIdx.x;
  const unsigned short* xb = x + (size_t)n * ACT_N;
  float s0 = 0.f, s1 = 0.f;
  for (int i = 0; i < 196; i++) {
    int pp = (i / 14 + 1) * 16 + (i % 14) + 1;
    unsigned int vv = *(const unsigned int*)(xb + pp * 512 + t * 2);
    s0 += b2f((unsigned short)vv);
    s1 += b2f((unsigned short)(vv >> 16));
  }
  out[(size_t)n * 1536 + 1024 + t * 2]     = s0 * (1.f / 196.f);
  out[(size_t)n * 1536 + 1024 + t * 2 + 1] = s1 * (1.f / 196.f);
}

extern "C" void kernel_launch(void* const* d_in, const int* in_sizes, int n_in,
                              void* d_out, int out_size, void* d_ws, size_t ws_size,
                              hipStream_t stream) {
  const float* x     = (const float*)d_in[0];
  const float* feat  = (const float*)d_in[1];
  const int*   rois  = (const int*)d_in[2];
  const float* w1    = (const float*)d_in[3];
  const float* w2    = (const float*)d_in[4];
  const float* wq    = (const float*)d_in[5];
  const float* wk    = (const float*)d_in[6];
  const float* wv    = (const float*)d_in[7];
  const float* wm    = (const float*)d_in[8];
  const float* gamma = (const float*)d_in[9];
  const float* beta  = (const float*)d_in[10];
  float* out = (float*)d_out;

  // ---- workspace layout ----
  // vt (6.42 MB) ALIASES [xp..W1g]: those are only used before the d-loop.
  float* wsf   = (float*)d_ws;
  float* xp    = wsf;                // 32768 f32
  float* bias1 = xp + 32768;         // 16384 f32
  float* stats = bias1 + 16384;      // 64 f32 (unused, kept for layout)
  float* attf  = stats + 64;         // 262144 f32 (unused, kept for layout)
  unsigned short* ub    = (unsigned short*)(attf + 262144);
  unsigned short* featT = ub;                    // 2097152 shorts
  unsigned short* W1g   = featT + 2097152;       // 524288 shorts
  unsigned short* Wg2   = W1g + 524288;          // 13*W3SZ shorts
  unsigned short* bufq  = Wg2 + 30670848;        // q/k/v contiguous
  unsigned short* bufk  = bufq + 4194304;
  unsigned short* bufv  = bufk + 4194304;
  unsigned short* bufx  = bufv + 4194304;
  unsigned short* vt    = (unsigned short*)d_ws; // 196*512*32 = 3,211,264 shorts
  float* gnpart = (float*)(bufx + 4194304);      // 196*32*2 f32

  // bufx border rows must be zero (only interior ever written by convs)
  hipMemsetAsync(bufx, 0, (size_t)4194304 * 2, stream);

  pool_max_kernel<<<8192, 256, 0, stream>>>(x, xp, out);
  bias1_kernel<<<4096, 256, 0, stream>>>(w1, xp, bias1);
  wprep3_kernel<<<dim3(16, 8, 13), 256, 0, stream>>>(w2, wq, wk, wv, wm, Wg2);
  w1prep_kernel<<<dim3(32, 8), 256, 0, stream>>>(w1, W1g);
  ftprep_kernel<<<dim3(4, 16, 8), 256, 0, stream>>>(feat, featT);

  // conv1: 1x1, K=1024, +bias1, relu, full 16x16 output -> bufq
  conv_mfma_kernel<1, 1024, 4, 4, 1, true, false, true, false>
      <<<dim3(8, 32), 256, 0, stream>>>(featT, rois, W1g, bias1, bufq);
  // conv2: valid 3x3 -> padded interior of bufx, relu
  conv_mfma_kernel<9, 512, 4, 4, 1, true, false, false, true>
      <<<dim3(8, 32), 256, 0, stream>>>(bufq, nullptr, Wg2, nullptr, bufx);

  for (int d = 0; d < 3; d++) {
    // q,k,v batched conv
    conv_mfma_kernel<9, 512, 4, 4, 1, false, false, false, true>
        <<<dim3(24, 32), 256, 0, stream>>>(bufx, nullptr,
            Wg2 + (size_t)(1 + 4 * d) * W3SZ, nullptr, bufq);
    vtrans_kernel<<<196, 256, 0, stream>>>(bufv, vt);
    attfused_kernel<<<256, 64, 0, stream>>>(bufq, bufk, vt, bufq, gnpart);
    gnapply3_kernel<<<dim3(2, 32), 256, 0, stream>>>(bufq, gnpart,
        gamma + d * 512, beta + d * 512);
    // wm conv + residual add into bufx
    conv_mfma_kernel<9, 512, 4, 4, 1, false, true, false, true>
        <<<dim3(8, 32), 256, 0, stream>>>(bufq, nullptr,
            Wg2 + (size_t)(4 + 4 * d) * W3SZ, nullptr, bufx);
  }

  fmean2_kernel<<<32, 256, 0, stream>>>(bufx, out);
}